// Round 1
// baseline (1205.879 us; speedup 1.0000x reference)
//
#include <hip/hip_runtime.h>

#define NN 100000   // nodes
#define NE 1600000  // edges
#define FD 128      // feature dim (4 heads x 32 ch)

// ---------------- edge sort (counting sort by dst) ----------------

__global__ void k_hist(const int* __restrict__ dst, int* __restrict__ cnt) {
    int e = blockIdx.x * 256 + threadIdx.x;
    if (e < NE) atomicAdd(&cnt[dst[e]], 1);
}

__global__ void k_scan1(const int* __restrict__ cnt, int* __restrict__ off, int* __restrict__ bsum) {
    __shared__ int sh[256];
    int t = threadIdx.x;
    int base = blockIdx.x * 1024 + t * 4;
    int v0 = (base + 0 < NN) ? cnt[base + 0] : 0;
    int v1 = (base + 1 < NN) ? cnt[base + 1] : 0;
    int v2 = (base + 2 < NN) ? cnt[base + 2] : 0;
    int v3 = (base + 3 < NN) ? cnt[base + 3] : 0;
    int tsum = v0 + v1 + v2 + v3;
    sh[t] = tsum;
    __syncthreads();
    for (int o = 1; o < 256; o <<= 1) {
        int x = (t >= o) ? sh[t - o] : 0;
        __syncthreads();
        sh[t] += x;
        __syncthreads();
    }
    int p = sh[t] - tsum;  // exclusive prefix within block
    if (t == 255) bsum[blockIdx.x] = sh[255];
    if (base + 0 < NN) { off[base + 0] = p; p += v0; }
    if (base + 1 < NN) { off[base + 1] = p; p += v1; }
    if (base + 2 < NN) { off[base + 2] = p; p += v2; }
    if (base + 3 < NN) { off[base + 3] = p; p += v3; }
}

__global__ void k_scan2(int* bsum, int nb) {
    if (threadIdx.x == 0) {
        int run = 0;
        for (int i = 0; i < nb; i++) { int v = bsum[i]; bsum[i] = run; run += v; }
    }
}

__global__ void k_add(int* off, const int* __restrict__ bsum) {
    int i = blockIdx.x * 256 + threadIdx.x;
    if (i < NN) off[i] += bsum[i >> 10];
    else if (i == NN) off[i] = NE;
}

__global__ void k_scatter(const int* __restrict__ src, const int* __restrict__ dst,
                          const int* __restrict__ off, int* __restrict__ cur,
                          int* __restrict__ ssrc) {
    int e = blockIdx.x * 256 + threadIdx.x;
    if (e < NE) {
        int d = dst[e];
        int p = off[d] + atomicAdd(&cur[d], 1);
        ssrc[p] = src[e];
    }
}

// ---------------- GEMM: C[n,128] = A[n,128] @ W[128,128] (f32) ----------------
// 64-row tile per block, x staged in LDS (padded), W streamed from global (L1/L2 hot).

__global__ __launch_bounds__(256) void k_gemm(const float* __restrict__ A,
                                              const float* __restrict__ W,
                                              float* __restrict__ C, int n) {
    __shared__ float sX[64][132];  // +4 pad: conflict-free b128 writes, 2-way b32 reads
    int t = threadIdx.x;
    int row0 = blockIdx.x * 64;
#pragma unroll
    for (int it = 0; it < 8; ++it) {
        int r = it * 8 + (t >> 5);
        int k4 = (t & 31) * 4;
        int gr = row0 + r;
        float4 v = make_float4(0.f, 0.f, 0.f, 0.f);
        if (gr < n) v = *(const float4*)(A + (size_t)gr * FD + k4);
        *(float4*)(&sX[r][k4]) = v;
    }
    __syncthreads();
    int tx = t & 15, ty = t >> 4;
    float4 acc0[4], acc1[4];
#pragma unroll
    for (int i = 0; i < 4; i++) {
        acc0[i] = make_float4(0.f, 0.f, 0.f, 0.f);
        acc1[i] = make_float4(0.f, 0.f, 0.f, 0.f);
    }
#pragma unroll 4
    for (int k = 0; k < 128; ++k) {
        float4 b0 = *(const float4*)(W + k * FD + tx * 4);
        float4 b1 = *(const float4*)(W + k * FD + 64 + tx * 4);
#pragma unroll
        for (int i = 0; i < 4; i++) {
            float a = sX[ty * 4 + i][k];
            acc0[i].x += a * b0.x; acc0[i].y += a * b0.y;
            acc0[i].z += a * b0.z; acc0[i].w += a * b0.w;
            acc1[i].x += a * b1.x; acc1[i].y += a * b1.y;
            acc1[i].z += a * b1.z; acc1[i].w += a * b1.w;
        }
    }
#pragma unroll
    for (int i = 0; i < 4; i++) {
        int gr = row0 + ty * 4 + i;
        if (gr < n) {
            *(float4*)(C + (size_t)gr * FD + tx * 4) = acc0[i];
            *(float4*)(C + (size_t)gr * FD + 64 + tx * 4) = acc1[i];
        }
    }
}

// ---------------- attention scores el/er: per (node, head) dot of 32 ----------------

__global__ void k_scores(const float* __restrict__ F, const float* __restrict__ al,
                         const float* __restrict__ ar, float* __restrict__ el,
                         float* __restrict__ er) {
    int idx = blockIdx.x * 256 + threadIdx.x;
    if (idx >= NN * 4) return;
    int h = idx & 3;
    const float4* f4 = (const float4*)(F + (size_t)idx * 32);  // node*128 + h*32 == idx*32
    const float4* a4 = (const float4*)(al + h * 32);
    const float4* b4 = (const float4*)(ar + h * 32);
    float sl = 0.f, sr = 0.f;
#pragma unroll
    for (int i = 0; i < 8; i++) {
        float4 f = f4[i], a = a4[i], b = b4[i];
        sl += f.x * a.x + f.y * a.y + f.z * a.z + f.w * a.w;
        sr += f.x * b.x + f.y * b.y + f.z * b.z + f.w * b.w;
    }
    el[idx] = sl;
    er[idx] = sr;
}

// ---------------- aggregation: one wave per dst node ----------------
// pass1: online softmax (16 edges x 4 heads across 64 lanes), butterfly merge
// pass2: per-edge alpha broadcast via shuffle, float2 feature accumulate

__global__ __launch_bounds__(256) void k_agg(const float* __restrict__ F,
                                             const float* __restrict__ el,
                                             const float* __restrict__ er,
                                             const int* __restrict__ off,
                                             const int* __restrict__ ssrc,
                                             float* __restrict__ out) {
    int wave = threadIdx.x >> 6;
    int lane = threadIdx.x & 63;
    int d = blockIdx.x * 4 + wave;
    if (d >= NN) return;
    int start = off[d];
    int deg = off[d + 1] - start;
    float2 acc = make_float2(0.f, 0.f);
    if (deg > 0) {
        int h = lane & 3;
        int eloc = lane >> 2;
        float er_h = er[d * 4 + h];
        float m = -1e30f, s = 0.f;
        for (int base = 0; base < deg; base += 16) {
            int i = base + eloc;
            if (i < deg) {
                int sid = ssrc[start + i];
                float v = el[sid * 4 + h] + er_h;
                float e = v > 0.f ? v : 0.2f * v;
                if (e <= m) {
                    s += __expf(e - m);
                } else {
                    s = s * __expf(m - e) + 1.f;
                    m = e;
                }
            }
        }
        // merge (m,s) across the 16 edge-groups (lanes differing in bits 2..5)
        for (int o = 4; o < 64; o <<= 1) {
            float om = __shfl_xor(m, o);
            float os = __shfl_xor(s, o);
            float nm = fmaxf(m, om);
            s = s * __expf(m - nm) + os * __expf(om - nm);
            m = nm;
        }
        float inv_s = 1.f / s;
        int hsel = lane >> 4;  // head owning channels {2*lane, 2*lane+1}
        for (int e = 0; e < deg; ++e) {
            int sid = ssrc[start + e];
            float v = el[sid * 4 + h] + er_h;
            float ee = v > 0.f ? v : 0.2f * v;
            float a = __expf(ee - m) * inv_s;     // valid on lanes 0..3 for h=0..3
            float alpha = __shfl(a, hsel, 64);
            float2 f = *(const float2*)(F + (size_t)sid * FD + lane * 2);
            acc.x += alpha * f.x;
            acc.y += alpha * f.y;
        }
    }
    acc.x = fmaxf(acc.x, 0.f);  // relu (layers 1,2 activation; layer 3 relu-after)
    acc.y = fmaxf(acc.y, 0.f);
    *(float2*)(out + (size_t)d * FD + lane * 2) = acc;
}

// ---------------- graph max-pool over nodes ----------------

__global__ void k_pool(const float* __restrict__ H, float* __restrict__ pooled) {
    int t = threadIdx.x;
    int c = t & 127;
    int seg = blockIdx.x * 2 + (t >> 7);
    const int NSEG = 256;
    int rpn = (NN + NSEG - 1) / NSEG;
    int r0 = seg * rpn;
    int r1 = min(NN, r0 + rpn);
    float m = 0.f;  // values are post-relu, >= 0
    for (int r = r0; r < r1; ++r) m = fmaxf(m, H[(size_t)r * FD + c]);
    atomicMax((int*)&pooled[c], __float_as_int(m));
}

// ---------------- final FC + softmax ----------------

__global__ void k_final(const float* __restrict__ pooled, const float* __restrict__ Wfc,
                        const float* __restrict__ bfc, float* __restrict__ outp) {
    int lane = threadIdx.x;  // 64 threads
    int j = lane & 7;
    int kk = lane >> 3;
    float partial = 0.f;
    for (int k = kk * 16; k < kk * 16 + 16; ++k) partial += pooled[k] * Wfc[k * 8 + j];
    for (int o = 8; o < 64; o <<= 1) partial += __shfl_xor(partial, o);
    float logit = partial + bfc[j];
    float mx = logit;
    for (int o = 1; o < 8; o <<= 1) mx = fmaxf(mx, __shfl_xor(mx, o));
    float ex = __expf(logit - mx);
    float sm = ex;
    for (int o = 1; o < 8; o <<= 1) sm += __shfl_xor(sm, o);
    if (lane < 8) outp[lane] = ex / sm;
}

// ---------------- launch ----------------

extern "C" void kernel_launch(void* const* d_in, const int* in_sizes, int n_in,
                              void* d_out, int out_size, void* d_ws, size_t ws_size,
                              hipStream_t stream) {
    const float* x   = (const float*)d_in[0];
    const int*   src = (const int*)d_in[1];
    const int*   dst = (const int*)d_in[2];
    const float* W1  = (const float*)d_in[3];
    const float* al1 = (const float*)d_in[4];
    const float* ar1 = (const float*)d_in[5];
    const float* W2  = (const float*)d_in[6];
    const float* al2 = (const float*)d_in[7];
    const float* ar2 = (const float*)d_in[8];
    const float* W3  = (const float*)d_in[9];
    const float* al3 = (const float*)d_in[10];
    const float* ar3 = (const float*)d_in[11];
    const float* Wfc = (const float*)d_in[12];
    const float* bfc = (const float*)d_in[13];
    float* out = (float*)d_out;

    char* p = (char*)d_ws;
    auto alloc = [&](size_t bytes) {
        char* r = p;
        p += (bytes + 255) & ~(size_t)255;
        return r;
    };
    float* F      = (float*)alloc((size_t)NN * FD * 4);
    float* H      = (float*)alloc((size_t)NN * FD * 4);
    float* el     = (float*)alloc((size_t)NN * 4 * 4);
    float* er     = (float*)alloc((size_t)NN * 4 * 4);
    int*   off    = (int*)alloc((size_t)(NN + 1) * 4);
    int*   cnt    = (int*)alloc((size_t)NN * 4);
    int*   bsum   = (int*)alloc(128 * 4);
    int*   ssrc   = (int*)alloc((size_t)NE * 4);
    float* pooled = (float*)alloc(128 * 4);

    const int EB = (NE + 255) / 256;          // 6250
    const int SB = (NN + 1023) / 1024;        // 98
    const int GB = (NN + 63) / 64;            // 1563
    const int AB = (NN + 3) / 4;              // 25000

    hipMemsetAsync(cnt, 0, (size_t)NN * 4, stream);
    hipMemsetAsync(pooled, 0, 128 * 4, stream);

    k_hist<<<EB, 256, 0, stream>>>(dst, cnt);
    k_scan1<<<SB, 256, 0, stream>>>(cnt, off, bsum);
    k_scan2<<<1, 64, 0, stream>>>(bsum, SB);
    k_add<<<(NN + 256) / 256, 256, 0, stream>>>(off, bsum);
    hipMemsetAsync(cnt, 0, (size_t)NN * 4, stream);
    k_scatter<<<EB, 256, 0, stream>>>(src, dst, off, cnt, ssrc);

    // layer 1
    k_gemm<<<GB, 256, 0, stream>>>(x, W1, F, NN);
    k_scores<<<(NN * 4 + 255) / 256, 256, 0, stream>>>(F, al1, ar1, el, er);
    k_agg<<<AB, 256, 0, stream>>>(F, el, er, off, ssrc, H);
    // layer 2
    k_gemm<<<GB, 256, 0, stream>>>(H, W2, F, NN);
    k_scores<<<(NN * 4 + 255) / 256, 256, 0, stream>>>(F, al2, ar2, el, er);
    k_agg<<<AB, 256, 0, stream>>>(F, el, er, off, ssrc, H);
    // layer 3 (+relu fused in k_agg, then pool)
    k_gemm<<<GB, 256, 0, stream>>>(H, W3, F, NN);
    k_scores<<<(NN * 4 + 255) / 256, 256, 0, stream>>>(F, al3, ar3, el, er);
    k_agg<<<AB, 256, 0, stream>>>(F, el, er, off, ssrc, H);

    k_pool<<<128, 256, 0, stream>>>(H, pooled);
    k_final<<<1, 64, 0, stream>>>(pooled, Wfc, bfc, out);
}

// Round 2
// 1003.835 us; speedup vs baseline: 1.2013x; 1.2013x over previous
//
#include <hip/hip_runtime.h>

#define NN 100000   // nodes
#define NE 1600000  // edges
#define FD 128      // feature dim (4 heads x 32 ch)

// ---------------- edge sort (counting sort by dst) ----------------

__global__ void k_hist(const int* __restrict__ dst, int* __restrict__ cnt) {
    int e = blockIdx.x * 256 + threadIdx.x;
    if (e < NE) atomicAdd(&cnt[dst[e]], 1);
}

__global__ void k_scan1(const int* __restrict__ cnt, int* __restrict__ off, int* __restrict__ bsum) {
    __shared__ int sh[256];
    int t = threadIdx.x;
    int base = blockIdx.x * 1024 + t * 4;
    int v0 = (base + 0 < NN) ? cnt[base + 0] : 0;
    int v1 = (base + 1 < NN) ? cnt[base + 1] : 0;
    int v2 = (base + 2 < NN) ? cnt[base + 2] : 0;
    int v3 = (base + 3 < NN) ? cnt[base + 3] : 0;
    int tsum = v0 + v1 + v2 + v3;
    sh[t] = tsum;
    __syncthreads();
    for (int o = 1; o < 256; o <<= 1) {
        int x = (t >= o) ? sh[t - o] : 0;
        __syncthreads();
        sh[t] += x;
        __syncthreads();
    }
    int p = sh[t] - tsum;  // exclusive prefix within block
    if (t == 255) bsum[blockIdx.x] = sh[255];
    if (base + 0 < NN) { off[base + 0] = p; p += v0; }
    if (base + 1 < NN) { off[base + 1] = p; p += v1; }
    if (base + 2 < NN) { off[base + 2] = p; p += v2; }
    if (base + 3 < NN) { off[base + 3] = p; p += v3; }
}

__global__ void k_scan2(int* bsum, int nb) {
    if (threadIdx.x == 0) {
        int run = 0;
        for (int i = 0; i < nb; i++) { int v = bsum[i]; bsum[i] = run; run += v; }
    }
}

__global__ void k_add(int* off, const int* __restrict__ bsum) {
    int i = blockIdx.x * 256 + threadIdx.x;
    if (i < NN) off[i] += bsum[i >> 10];
    else if (i == NN) off[i] = NE;
}

__global__ void k_scatter(const int* __restrict__ src, const int* __restrict__ dst,
                          const int* __restrict__ off, int* __restrict__ cur,
                          int* __restrict__ ssrc) {
    int e = blockIdx.x * 256 + threadIdx.x;
    if (e < NE) {
        int d = dst[e];
        int p = off[d] + atomicAdd(&cur[d], 1);
        ssrc[p] = src[e];
    }
}

// ---------------- GEMM: C[n,128] = A[n,128] @ W[128,128] (f32) ----------------

__global__ __launch_bounds__(256) void k_gemm(const float* __restrict__ A,
                                              const float* __restrict__ W,
                                              float* __restrict__ C, int n) {
    __shared__ float sX[64][132];  // +4 pad
    int t = threadIdx.x;
    int row0 = blockIdx.x * 64;
#pragma unroll
    for (int it = 0; it < 8; ++it) {
        int r = it * 8 + (t >> 5);
        int k4 = (t & 31) * 4;
        int gr = row0 + r;
        float4 v = make_float4(0.f, 0.f, 0.f, 0.f);
        if (gr < n) v = *(const float4*)(A + (size_t)gr * FD + k4);
        *(float4*)(&sX[r][k4]) = v;
    }
    __syncthreads();
    int tx = t & 15, ty = t >> 4;
    float4 acc0[4], acc1[4];
#pragma unroll
    for (int i = 0; i < 4; i++) {
        acc0[i] = make_float4(0.f, 0.f, 0.f, 0.f);
        acc1[i] = make_float4(0.f, 0.f, 0.f, 0.f);
    }
#pragma unroll 4
    for (int k = 0; k < 128; ++k) {
        float4 b0 = *(const float4*)(W + k * FD + tx * 4);
        float4 b1 = *(const float4*)(W + k * FD + 64 + tx * 4);
#pragma unroll
        for (int i = 0; i < 4; i++) {
            float a = sX[ty * 4 + i][k];
            acc0[i].x += a * b0.x; acc0[i].y += a * b0.y;
            acc0[i].z += a * b0.z; acc0[i].w += a * b0.w;
            acc1[i].x += a * b1.x; acc1[i].y += a * b1.y;
            acc1[i].z += a * b1.z; acc1[i].w += a * b1.w;
        }
    }
#pragma unroll
    for (int i = 0; i < 4; i++) {
        int gr = row0 + ty * 4 + i;
        if (gr < n) {
            *(float4*)(C + (size_t)gr * FD + tx * 4) = acc0[i];
            *(float4*)(C + (size_t)gr * FD + 64 + tx * 4) = acc1[i];
        }
    }
}

// ---------------- attention scores el/er ----------------

__global__ void k_scores(const float* __restrict__ F, const float* __restrict__ al,
                         const float* __restrict__ ar, float* __restrict__ el,
                         float* __restrict__ er) {
    int idx = blockIdx.x * 256 + threadIdx.x;
    if (idx >= NN * 4) return;
    int h = idx & 3;
    const float4* f4 = (const float4*)(F + (size_t)idx * 32);
    const float4* a4 = (const float4*)(al + h * 32);
    const float4* b4 = (const float4*)(ar + h * 32);
    float sl = 0.f, sr = 0.f;
#pragma unroll
    for (int i = 0; i < 8; i++) {
        float4 f = f4[i], a = a4[i], b = b4[i];
        sl += f.x * a.x + f.y * a.y + f.z * a.z + f.w * a.w;
        sr += f.x * b.x + f.y * b.y + f.z * b.z + f.w * b.w;
    }
    el[idx] = sl;
    er[idx] = sr;
}

// ---------------- aggregation: one wave per dst node ----------------
// pass1: online softmax (16 edges x 4 heads across 64 lanes), butterfly merge
// pass2: chunked — compute 16 alphas in parallel, then 16 independent row
//        loads per chunk (4-unrolled) for memory-level parallelism.

__global__ __launch_bounds__(256) void k_agg(const float* __restrict__ F,
                                             const float* __restrict__ el,
                                             const float* __restrict__ er,
                                             const int* __restrict__ off,
                                             const int* __restrict__ ssrc,
                                             float* __restrict__ out) {
    int wave = threadIdx.x >> 6;
    int lane = threadIdx.x & 63;
    int d = blockIdx.x * 4 + wave;
    if (d >= NN) return;
    int start = off[d];
    int deg = off[d + 1] - start;
    float2 acc = make_float2(0.f, 0.f);
    if (deg > 0) {
        int h = lane & 3;
        int eloc = lane >> 2;
        float er_h = er[d * 4 + h];
        float m = -1e30f, s = 0.f;
        for (int base = 0; base < deg; base += 16) {
            int i = base + eloc;
            if (i < deg) {
                int sid = ssrc[start + i];
                float v = el[sid * 4 + h] + er_h;
                float e = v > 0.f ? v : 0.2f * v;
                if (e <= m) {
                    s += __expf(e - m);
                } else {
                    s = s * __expf(m - e) + 1.f;
                    m = e;
                }
            }
        }
        // merge (m,s) across the 16 edge-groups; result per-head on every lane
        for (int o = 4; o < 64; o <<= 1) {
            float om = __shfl_xor(m, o);
            float os = __shfl_xor(s, o);
            float nm = fmaxf(m, om);
            s = s * __expf(m - nm) + os * __expf(om - nm);
            m = nm;
        }
        float inv_s = 1.f / s;
        int hsel = lane >> 4;  // head owning channels {2*lane, 2*lane+1}
        for (int base = 0; base < deg; base += 16) {
            int i = base + eloc;
            float a = 0.f;
            int sid = 0;
            if (i < deg) {
                sid = ssrc[start + i];
                float v = el[sid * 4 + h] + er_h;
                float e2 = v > 0.f ? v : 0.2f * v;
                a = __expf(e2 - m) * inv_s;
            }
            int lim = deg - base;
            if (lim > 16) lim = 16;
            int j = 0;
            for (; j + 4 <= lim; j += 4) {
                int   s0 = __shfl(sid, (j + 0) * 4);
                int   s1 = __shfl(sid, (j + 1) * 4);
                int   s2 = __shfl(sid, (j + 2) * 4);
                int   s3 = __shfl(sid, (j + 3) * 4);
                float a0 = __shfl(a, (j + 0) * 4 + hsel);
                float a1 = __shfl(a, (j + 1) * 4 + hsel);
                float a2 = __shfl(a, (j + 2) * 4 + hsel);
                float a3 = __shfl(a, (j + 3) * 4 + hsel);
                float2 f0 = *(const float2*)(F + (size_t)s0 * FD + lane * 2);
                float2 f1 = *(const float2*)(F + (size_t)s1 * FD + lane * 2);
                float2 f2 = *(const float2*)(F + (size_t)s2 * FD + lane * 2);
                float2 f3 = *(const float2*)(F + (size_t)s3 * FD + lane * 2);
                acc.x = fmaf(a0, f0.x, acc.x); acc.y = fmaf(a0, f0.y, acc.y);
                acc.x = fmaf(a1, f1.x, acc.x); acc.y = fmaf(a1, f1.y, acc.y);
                acc.x = fmaf(a2, f2.x, acc.x); acc.y = fmaf(a2, f2.y, acc.y);
                acc.x = fmaf(a3, f3.x, acc.x); acc.y = fmaf(a3, f3.y, acc.y);
            }
            for (; j < lim; ++j) {
                int   sj = __shfl(sid, j * 4);
                float aj = __shfl(a, j * 4 + hsel);
                float2 f = *(const float2*)(F + (size_t)sj * FD + lane * 2);
                acc.x = fmaf(aj, f.x, acc.x);
                acc.y = fmaf(aj, f.y, acc.y);
            }
        }
    }
    acc.x = fmaxf(acc.x, 0.f);  // relu
    acc.y = fmaxf(acc.y, 0.f);
    *(float2*)(out + (size_t)d * FD + lane * 2) = acc;
}

// ---------------- graph max-pool over nodes ----------------

__global__ void k_pool(const float* __restrict__ H, float* __restrict__ pooled) {
    int t = threadIdx.x;
    int c = t & 127;
    int seg = blockIdx.x * 2 + (t >> 7);
    const int NSEG = 256;
    int rpn = (NN + NSEG - 1) / NSEG;
    int r0 = seg * rpn;
    int r1 = min(NN, r0 + rpn);
    float m = 0.f;  // values are post-relu, >= 0
    for (int r = r0; r < r1; ++r) m = fmaxf(m, H[(size_t)r * FD + c]);
    atomicMax((int*)&pooled[c], __float_as_int(m));
}

// ---------------- final FC + softmax ----------------

__global__ void k_final(const float* __restrict__ pooled, const float* __restrict__ Wfc,
                        const float* __restrict__ bfc, float* __restrict__ outp) {
    int lane = threadIdx.x;  // 64 threads
    int j = lane & 7;
    int kk = lane >> 3;
    float partial = 0.f;
    for (int k = kk * 16; k < kk * 16 + 16; ++k) partial += pooled[k] * Wfc[k * 8 + j];
    for (int o = 8; o < 64; o <<= 1) partial += __shfl_xor(partial, o);
    float logit = partial + bfc[j];
    float mx = logit;
    for (int o = 1; o < 8; o <<= 1) mx = fmaxf(mx, __shfl_xor(mx, o));
    float ex = __expf(logit - mx);
    float sm = ex;
    for (int o = 1; o < 8; o <<= 1) sm += __shfl_xor(sm, o);
    if (lane < 8) outp[lane] = ex / sm;
}

// ---------------- launch ----------------

extern "C" void kernel_launch(void* const* d_in, const int* in_sizes, int n_in,
                              void* d_out, int out_size, void* d_ws, size_t ws_size,
                              hipStream_t stream) {
    const float* x   = (const float*)d_in[0];
    const int*   src = (const int*)d_in[1];
    const int*   dst = (const int*)d_in[2];
    const float* W1  = (const float*)d_in[3];
    const float* al1 = (const float*)d_in[4];
    const float* ar1 = (const float*)d_in[5];
    const float* W2  = (const float*)d_in[6];
    const float* al2 = (const float*)d_in[7];
    const float* ar2 = (const float*)d_in[8];
    const float* W3  = (const float*)d_in[9];
    const float* al3 = (const float*)d_in[10];
    const float* ar3 = (const float*)d_in[11];
    const float* Wfc = (const float*)d_in[12];
    const float* bfc = (const float*)d_in[13];
    float* out = (float*)d_out;

    char* p = (char*)d_ws;
    auto alloc = [&](size_t bytes) {
        char* r = p;
        p += (bytes + 255) & ~(size_t)255;
        return r;
    };
    float* F      = (float*)alloc((size_t)NN * FD * 4);
    float* H      = (float*)alloc((size_t)NN * FD * 4);
    float* el     = (float*)alloc((size_t)NN * 4 * 4);
    float* er     = (float*)alloc((size_t)NN * 4 * 4);
    int*   off    = (int*)alloc((size_t)(NN + 1) * 4);
    int*   cnt    = (int*)alloc((size_t)NN * 4);
    int*   bsum   = (int*)alloc(128 * 4);
    int*   ssrc   = (int*)alloc((size_t)NE * 4);
    float* pooled = (float*)alloc(128 * 4);

    const int EB = (NE + 255) / 256;
    const int SB = (NN + 1023) / 1024;
    const int GB = (NN + 63) / 64;
    const int AB = (NN + 3) / 4;

    hipMemsetAsync(cnt, 0, (size_t)NN * 4, stream);
    hipMemsetAsync(pooled, 0, 128 * 4, stream);

    k_hist<<<EB, 256, 0, stream>>>(dst, cnt);
    k_scan1<<<SB, 256, 0, stream>>>(cnt, off, bsum);
    k_scan2<<<1, 64, 0, stream>>>(bsum, SB);
    k_add<<<(NN + 256) / 256, 256, 0, stream>>>(off, bsum);
    hipMemsetAsync(cnt, 0, (size_t)NN * 4, stream);
    k_scatter<<<EB, 256, 0, stream>>>(src, dst, off, cnt, ssrc);

    // layer 1
    k_gemm<<<GB, 256, 0, stream>>>(x, W1, F, NN);
    k_scores<<<(NN * 4 + 255) / 256, 256, 0, stream>>>(F, al1, ar1, el, er);
    k_agg<<<AB, 256, 0, stream>>>(F, el, er, off, ssrc, H);
    // layer 2
    k_gemm<<<GB, 256, 0, stream>>>(H, W2, F, NN);
    k_scores<<<(NN * 4 + 255) / 256, 256, 0, stream>>>(F, al2, ar2, el, er);
    k_agg<<<AB, 256, 0, stream>>>(F, el, er, off, ssrc, H);
    // layer 3
    k_gemm<<<GB, 256, 0, stream>>>(H, W3, F, NN);
    k_scores<<<(NN * 4 + 255) / 256, 256, 0, stream>>>(F, al3, ar3, el, er);
    k_agg<<<AB, 256, 0, stream>>>(F, el, er, off, ssrc, H);

    k_pool<<<128, 256, 0, stream>>>(H, pooled);
    k_final<<<1, 64, 0, stream>>>(pooled, Wfc, bfc, out);
}

// Round 3
// 834.439 us; speedup vs baseline: 1.4451x; 1.2030x over previous
//
#include <hip/hip_runtime.h>

#define NN 100000   // nodes
#define NE 1600000  // edges
#define FD 128      // feature dim (4 heads x 32 ch)

// ---------------- helpers ----------------

__device__ __forceinline__ unsigned short f2bf(float x) {
    unsigned int u = __float_as_uint(x);
    u += 0x7fffu + ((u >> 16) & 1u);   // round-to-nearest-even
    return (unsigned short)(u >> 16);
}

// ---------------- edge sort (counting sort by dst) ----------------

__global__ void k_hist(const int* __restrict__ dst, int* __restrict__ cnt) {
    int e = blockIdx.x * 256 + threadIdx.x;
    if (e < NE) atomicAdd(&cnt[dst[e]], 1);
}

__global__ void k_scan1(const int* __restrict__ cnt, int* __restrict__ off, int* __restrict__ bsum) {
    __shared__ int sh[256];
    int t = threadIdx.x;
    int base = blockIdx.x * 1024 + t * 4;
    int v0 = (base + 0 < NN) ? cnt[base + 0] : 0;
    int v1 = (base + 1 < NN) ? cnt[base + 1] : 0;
    int v2 = (base + 2 < NN) ? cnt[base + 2] : 0;
    int v3 = (base + 3 < NN) ? cnt[base + 3] : 0;
    int tsum = v0 + v1 + v2 + v3;
    sh[t] = tsum;
    __syncthreads();
    for (int o = 1; o < 256; o <<= 1) {
        int x = (t >= o) ? sh[t - o] : 0;
        __syncthreads();
        sh[t] += x;
        __syncthreads();
    }
    int p = sh[t] - tsum;
    if (t == 255) bsum[blockIdx.x] = sh[255];
    if (base + 0 < NN) { off[base + 0] = p; p += v0; }
    if (base + 1 < NN) { off[base + 1] = p; p += v1; }
    if (base + 2 < NN) { off[base + 2] = p; p += v2; }
    if (base + 3 < NN) { off[base + 3] = p; p += v3; }
}

__global__ void k_scan2(int* bsum, int nb) {
    if (threadIdx.x == 0) {
        int run = 0;
        for (int i = 0; i < nb; i++) { int v = bsum[i]; bsum[i] = run; run += v; }
    }
}

__global__ void k_add(int* off, const int* __restrict__ bsum) {
    int i = blockIdx.x * 256 + threadIdx.x;
    if (i < NN) off[i] += bsum[i >> 10];
    else if (i == NN) off[i] = NE;
}

__global__ void k_scatter(const int* __restrict__ src, const int* __restrict__ dst,
                          const int* __restrict__ off, int* __restrict__ cur,
                          int* __restrict__ ssrc) {
    int e = blockIdx.x * 256 + threadIdx.x;
    if (e < NE) {
        int d = dst[e];
        int p = off[d] + atomicAdd(&cur[d], 1);
        ssrc[p] = src[e];
    }
}

// ---------------- GEMM: Fb[n,128](bf16) = A[n,128](f32) @ W[128,128](f32) ----------------

__global__ __launch_bounds__(256) void k_gemm(const float* __restrict__ A,
                                              const float* __restrict__ W,
                                              unsigned short* __restrict__ Fb, int n) {
    __shared__ float sX[64][132];  // +4 pad
    int t = threadIdx.x;
    int row0 = blockIdx.x * 64;
#pragma unroll
    for (int it = 0; it < 8; ++it) {
        int r = it * 8 + (t >> 5);
        int k4 = (t & 31) * 4;
        int gr = row0 + r;
        float4 v = make_float4(0.f, 0.f, 0.f, 0.f);
        if (gr < n) v = *(const float4*)(A + (size_t)gr * FD + k4);
        *(float4*)(&sX[r][k4]) = v;
    }
    __syncthreads();
    int tx = t & 15, ty = t >> 4;
    float4 acc0[4], acc1[4];
#pragma unroll
    for (int i = 0; i < 4; i++) {
        acc0[i] = make_float4(0.f, 0.f, 0.f, 0.f);
        acc1[i] = make_float4(0.f, 0.f, 0.f, 0.f);
    }
#pragma unroll 4
    for (int k = 0; k < 128; ++k) {
        float4 b0 = *(const float4*)(W + k * FD + tx * 4);
        float4 b1 = *(const float4*)(W + k * FD + 64 + tx * 4);
#pragma unroll
        for (int i = 0; i < 4; i++) {
            float a = sX[ty * 4 + i][k];
            acc0[i].x += a * b0.x; acc0[i].y += a * b0.y;
            acc0[i].z += a * b0.z; acc0[i].w += a * b0.w;
            acc1[i].x += a * b1.x; acc1[i].y += a * b1.y;
            acc1[i].z += a * b1.z; acc1[i].w += a * b1.w;
        }
    }
#pragma unroll
    for (int i = 0; i < 4; i++) {
        int gr = row0 + ty * 4 + i;
        if (gr < n) {
            ushort4 o0, o1;
            o0.x = f2bf(acc0[i].x); o0.y = f2bf(acc0[i].y);
            o0.z = f2bf(acc0[i].z); o0.w = f2bf(acc0[i].w);
            o1.x = f2bf(acc1[i].x); o1.y = f2bf(acc1[i].y);
            o1.z = f2bf(acc1[i].z); o1.w = f2bf(acc1[i].w);
            *(ushort4*)(Fb + (size_t)gr * FD + tx * 4) = o0;
            *(ushort4*)(Fb + (size_t)gr * FD + 64 + tx * 4) = o1;
        }
    }
}

// ---------------- attention scores el/er from bf16 features (f32 math) ----------------

__global__ void k_scores(const unsigned short* __restrict__ Fb, const float* __restrict__ al,
                         const float* __restrict__ ar, float* __restrict__ el,
                         float* __restrict__ er) {
    int idx = blockIdx.x * 256 + threadIdx.x;
    if (idx >= NN * 4) return;
    int h = idx & 3;
    const uint4* f16 = (const uint4*)(Fb + (size_t)idx * 32);
    const float* a = al + h * 32;
    const float* b = ar + h * 32;
    float sl = 0.f, sr = 0.f;
#pragma unroll
    for (int i = 0; i < 4; i++) {
        uint4 u = f16[i];
        float f[8];
        f[0] = __uint_as_float(u.x << 16); f[1] = __uint_as_float(u.x & 0xffff0000u);
        f[2] = __uint_as_float(u.y << 16); f[3] = __uint_as_float(u.y & 0xffff0000u);
        f[4] = __uint_as_float(u.z << 16); f[5] = __uint_as_float(u.z & 0xffff0000u);
        f[6] = __uint_as_float(u.w << 16); f[7] = __uint_as_float(u.w & 0xffff0000u);
#pragma unroll
        for (int k2 = 0; k2 < 8; k2++) {
            sl = fmaf(f[k2], a[i * 8 + k2], sl);
            sr = fmaf(f[k2], b[i * 8 + k2], sr);
        }
    }
    el[idx] = sl;
    er[idx] = sr;
}

// ---------------- aggregation: one wave per dst node ----------------
// pass1: online softmax (16 edges x 4 heads across 64 lanes), butterfly merge
// pass2: 16-edge chunks, fully unrolled — sid via readlane (SALU), alpha via
//        1 bpermute/edge, 16 independent bf16 row loads in flight.

__global__ __launch_bounds__(256) void k_agg(const unsigned short* __restrict__ Fb,
                                             const float* __restrict__ el,
                                             const float* __restrict__ er,
                                             const int* __restrict__ off,
                                             const int* __restrict__ ssrc,
                                             float* __restrict__ out) {
    int wave = threadIdx.x >> 6;
    int lane = threadIdx.x & 63;
    int d = blockIdx.x * 4 + wave;
    if (d >= NN) return;
    int start = off[d];
    int deg = off[d + 1] - start;
    float2 acc = make_float2(0.f, 0.f);
    if (deg > 0) {
        int h = lane & 3;
        int eloc = lane >> 2;
        float er_h = er[d * 4 + h];
        float m = -1e30f, s = 0.f;
        for (int base = 0; base < deg; base += 16) {
            int i = base + eloc;
            if (i < deg) {
                int sid = ssrc[start + i];
                float v = el[sid * 4 + h] + er_h;
                float e = v > 0.f ? v : 0.2f * v;
                if (e <= m) {
                    s += __expf(e - m);
                } else {
                    s = s * __expf(m - e) + 1.f;
                    m = e;
                }
            }
        }
        for (int o = 4; o < 64; o <<= 1) {
            float om = __shfl_xor(m, o);
            float os = __shfl_xor(s, o);
            float nm = fmaxf(m, om);
            s = s * __expf(m - nm) + os * __expf(om - nm);
            m = nm;
        }
        float inv_s = 1.f / s;
        int hsel = lane >> 4;  // head owning channels {2*lane, 2*lane+1}
        for (int base = 0; base < deg; base += 16) {
            int i = base + eloc;
            float a = 0.f;
            int sid = 0;  // invalid edges -> row 0 with alpha 0 (L1-hot, harmless)
            if (i < deg) {
                sid = ssrc[start + i];
                float v = el[sid * 4 + h] + er_h;
                float e2 = v > 0.f ? v : 0.2f * v;
                a = __expf(e2 - m) * inv_s;
            }
            int sids[16];
            float a16[16];
#pragma unroll
            for (int j = 0; j < 16; j++) {
                sids[j] = __builtin_amdgcn_readlane(sid, 4 * j);
                a16[j] = __shfl(a, 4 * j + hsel, 64);
            }
            unsigned int u[16];
#pragma unroll
            for (int j = 0; j < 16; j++) {
                u[j] = *(const unsigned int*)(Fb + (size_t)sids[j] * FD + lane * 2);
            }
#pragma unroll
            for (int j = 0; j < 16; j++) {
                float fx = __uint_as_float(u[j] << 16);
                float fy = __uint_as_float(u[j] & 0xffff0000u);
                acc.x = fmaf(a16[j], fx, acc.x);
                acc.y = fmaf(a16[j], fy, acc.y);
            }
        }
    }
    acc.x = fmaxf(acc.x, 0.f);  // relu
    acc.y = fmaxf(acc.y, 0.f);
    *(float2*)(out + (size_t)d * FD + lane * 2) = acc;
}

// ---------------- graph max-pool over nodes ----------------

__global__ void k_pool(const float* __restrict__ H, float* __restrict__ pooled) {
    int t = threadIdx.x;
    int c = t & 127;
    int seg = blockIdx.x * 2 + (t >> 7);
    const int NSEG = 256;
    int rpn = (NN + NSEG - 1) / NSEG;
    int r0 = seg * rpn;
    int r1 = min(NN, r0 + rpn);
    float m = 0.f;
    for (int r = r0; r < r1; ++r) m = fmaxf(m, H[(size_t)r * FD + c]);
    atomicMax((int*)&pooled[c], __float_as_int(m));
}

// ---------------- final FC + softmax ----------------

__global__ void k_final(const float* __restrict__ pooled, const float* __restrict__ Wfc,
                        const float* __restrict__ bfc, float* __restrict__ outp) {
    int lane = threadIdx.x;
    int j = lane & 7;
    int kk = lane >> 3;
    float partial = 0.f;
    for (int k = kk * 16; k < kk * 16 + 16; ++k) partial += pooled[k] * Wfc[k * 8 + j];
    for (int o = 8; o < 64; o <<= 1) partial += __shfl_xor(partial, o);
    float logit = partial + bfc[j];
    float mx = logit;
    for (int o = 1; o < 8; o <<= 1) mx = fmaxf(mx, __shfl_xor(mx, o));
    float ex = __expf(logit - mx);
    float sm = ex;
    for (int o = 1; o < 8; o <<= 1) sm += __shfl_xor(sm, o);
    if (lane < 8) outp[lane] = ex / sm;
}

// ---------------- launch ----------------

extern "C" void kernel_launch(void* const* d_in, const int* in_sizes, int n_in,
                              void* d_out, int out_size, void* d_ws, size_t ws_size,
                              hipStream_t stream) {
    const float* x   = (const float*)d_in[0];
    const int*   src = (const int*)d_in[1];
    const int*   dst = (const int*)d_in[2];
    const float* W1  = (const float*)d_in[3];
    const float* al1 = (const float*)d_in[4];
    const float* ar1 = (const float*)d_in[5];
    const float* W2  = (const float*)d_in[6];
    const float* al2 = (const float*)d_in[7];
    const float* ar2 = (const float*)d_in[8];
    const float* W3  = (const float*)d_in[9];
    const float* al3 = (const float*)d_in[10];
    const float* ar3 = (const float*)d_in[11];
    const float* Wfc = (const float*)d_in[12];
    const float* bfc = (const float*)d_in[13];
    float* out = (float*)d_out;

    char* p = (char*)d_ws;
    auto alloc = [&](size_t bytes) {
        char* r = p;
        p += (bytes + 255) & ~(size_t)255;
        return r;
    };
    unsigned short* Fb = (unsigned short*)alloc((size_t)NN * FD * 2);
    float* H      = (float*)alloc((size_t)NN * FD * 4);
    float* el     = (float*)alloc((size_t)NN * 4 * 4);
    float* er     = (float*)alloc((size_t)NN * 4 * 4);
    int*   off    = (int*)alloc((size_t)(NN + 1) * 4);
    int*   cnt    = (int*)alloc((size_t)NN * 4);
    int*   bsum   = (int*)alloc(128 * 4);
    int*   ssrc   = (int*)alloc((size_t)NE * 4);
    float* pooled = (float*)alloc(128 * 4);

    const int EB = (NE + 255) / 256;
    const int SB = (NN + 1023) / 1024;
    const int GB = (NN + 63) / 64;
    const int AB = (NN + 3) / 4;

    hipMemsetAsync(cnt, 0, (size_t)NN * 4, stream);
    hipMemsetAsync(pooled, 0, 128 * 4, stream);

    k_hist<<<EB, 256, 0, stream>>>(dst, cnt);
    k_scan1<<<SB, 256, 0, stream>>>(cnt, off, bsum);
    k_scan2<<<1, 64, 0, stream>>>(bsum, SB);
    k_add<<<(NN + 256) / 256, 256, 0, stream>>>(off, bsum);
    hipMemsetAsync(cnt, 0, (size_t)NN * 4, stream);
    k_scatter<<<EB, 256, 0, stream>>>(src, dst, off, cnt, ssrc);

    // layer 1
    k_gemm<<<GB, 256, 0, stream>>>(x, W1, Fb, NN);
    k_scores<<<(NN * 4 + 255) / 256, 256, 0, stream>>>(Fb, al1, ar1, el, er);
    k_agg<<<AB, 256, 0, stream>>>(Fb, el, er, off, ssrc, H);
    // layer 2
    k_gemm<<<GB, 256, 0, stream>>>(H, W2, Fb, NN);
    k_scores<<<(NN * 4 + 255) / 256, 256, 0, stream>>>(Fb, al2, ar2, el, er);
    k_agg<<<AB, 256, 0, stream>>>(Fb, el, er, off, ssrc, H);
    // layer 3
    k_gemm<<<GB, 256, 0, stream>>>(H, W3, Fb, NN);
    k_scores<<<(NN * 4 + 255) / 256, 256, 0, stream>>>(Fb, al3, ar3, el, er);
    k_agg<<<AB, 256, 0, stream>>>(Fb, el, er, off, ssrc, H);

    k_pool<<<128, 256, 0, stream>>>(H, pooled);
    k_final<<<1, 64, 0, stream>>>(pooled, Wfc, bfc, out);
}

// Round 4
// 777.000 us; speedup vs baseline: 1.5520x; 1.0739x over previous
//
#include <hip/hip_runtime.h>

#define NN 100000   // nodes
#define NE 1600000  // edges
#define FD 128      // feature dim (4 heads x 32 ch)
#define NB 391      // ceil(NN/256) dst-buckets
#define CHUNK 8192  // edges per k_bucket block

// ---------------- helpers ----------------

__device__ __forceinline__ unsigned short f2bf(float x) {
    unsigned int u = __float_as_uint(x);
    u += 0x7fffu + ((u >> 16) & 1u);   // round-to-nearest-even
    return (unsigned short)(u >> 16);
}

// ---------------- per-node degree histogram + scan -> CSR offsets ----------------

__global__ void k_hist(const int* __restrict__ dst, int* __restrict__ cnt) {
    int e = blockIdx.x * 256 + threadIdx.x;
    if (e < NE) atomicAdd(&cnt[dst[e]], 1);
}

__global__ void k_scan1(const int* __restrict__ cnt, int* __restrict__ off, int* __restrict__ bsum) {
    __shared__ int sh[256];
    int t = threadIdx.x;
    int base = blockIdx.x * 1024 + t * 4;
    int v0 = (base + 0 < NN) ? cnt[base + 0] : 0;
    int v1 = (base + 1 < NN) ? cnt[base + 1] : 0;
    int v2 = (base + 2 < NN) ? cnt[base + 2] : 0;
    int v3 = (base + 3 < NN) ? cnt[base + 3] : 0;
    int tsum = v0 + v1 + v2 + v3;
    sh[t] = tsum;
    __syncthreads();
    for (int o = 1; o < 256; o <<= 1) {
        int x = (t >= o) ? sh[t - o] : 0;
        __syncthreads();
        sh[t] += x;
        __syncthreads();
    }
    int p = sh[t] - tsum;
    if (t == 255) bsum[blockIdx.x] = sh[255];
    if (base + 0 < NN) { off[base + 0] = p; p += v0; }
    if (base + 1 < NN) { off[base + 1] = p; p += v1; }
    if (base + 2 < NN) { off[base + 2] = p; p += v2; }
    if (base + 3 < NN) { off[base + 3] = p; p += v3; }
}

__global__ void k_scan2(int* bsum, int nb) {
    if (threadIdx.x == 0) {
        int run = 0;
        for (int i = 0; i < nb; i++) { int v = bsum[i]; bsum[i] = run; run += v; }
    }
}

__global__ void k_add(int* off, const int* __restrict__ bsum) {
    int i = blockIdx.x * 256 + threadIdx.x;
    if (i < NN) off[i] += bsum[i >> 10];
    else if (i == NN) off[i] = NE;
}

// ---------------- phase A: bucket edges by dst>>8 into CSR bucket regions ----------------
// pairs[pos] = src | (dst&255)<<17  (src<2^17, local dst 8 bits)

__global__ __launch_bounds__(256) void k_bucket(const int* __restrict__ src,
                                                const int* __restrict__ dst,
                                                const int* __restrict__ off,
                                                int* __restrict__ gcur,
                                                unsigned int* __restrict__ pairs) {
    __shared__ int scnt[NB];
    __shared__ int sbase[NB];
    int t = threadIdx.x;
    for (int i = t; i < NB; i += 256) scnt[i] = 0;
    __syncthreads();
    int e0 = blockIdx.x * CHUNK;
    int e1 = min(e0 + CHUNK, NE);
    for (int i = e0 + t; i < e1; i += 256) {
        atomicAdd(&scnt[dst[i] >> 8], 1);
    }
    __syncthreads();
    for (int i = t; i < NB; i += 256) {
        int c = scnt[i];
        sbase[i] = (c > 0) ? (off[i << 8] + atomicAdd(&gcur[i], c)) : 0;
        scnt[i] = 0;  // reuse as local cursor
    }
    __syncthreads();
    for (int i = e0 + t; i < e1; i += 256) {
        int d = dst[i];
        int b = d >> 8;
        int r = atomicAdd(&scnt[b], 1);
        pairs[sbase[b] + r] = (unsigned int)src[i] | ((unsigned int)(d & 255) << 17);
    }
}

// ---------------- phase B: within-bucket counting sort -> ssrc (CSR adjacency) ----------------

__global__ __launch_bounds__(256) void k_bsort(const unsigned int* __restrict__ pairs,
                                               const int* __restrict__ off,
                                               int* __restrict__ ssrc) {
    __shared__ int cur[256];
    int t = threadIdx.x;
    int b = blockIdx.x;
    int nstart = b << 8;
    cur[t] = off[min(nstart + t, NN)];  // global write cursor for node nstart+t
    __syncthreads();
    int estart = off[nstart];
    int eend = off[min(nstart + 256, NN)];
    for (int i = estart + t; i < eend; i += 256) {
        unsigned int p = pairs[i];
        int ldst = (p >> 17) & 255;
        int pos = atomicAdd(&cur[ldst], 1);
        ssrc[pos] = (int)(p & 0x1ffffu);
    }
}

// ---------------- GEMM: Fb[n,128](bf16) = A[n,128](f32) @ W[128,128](f32) ----------------

__global__ __launch_bounds__(256) void k_gemm(const float* __restrict__ A,
                                              const float* __restrict__ W,
                                              unsigned short* __restrict__ Fb, int n) {
    __shared__ float sX[64][132];  // +4 pad
    int t = threadIdx.x;
    int row0 = blockIdx.x * 64;
#pragma unroll
    for (int it = 0; it < 8; ++it) {
        int r = it * 8 + (t >> 5);
        int k4 = (t & 31) * 4;
        int gr = row0 + r;
        float4 v = make_float4(0.f, 0.f, 0.f, 0.f);
        if (gr < n) v = *(const float4*)(A + (size_t)gr * FD + k4);
        *(float4*)(&sX[r][k4]) = v;
    }
    __syncthreads();
    int tx = t & 15, ty = t >> 4;
    float4 acc0[4], acc1[4];
#pragma unroll
    for (int i = 0; i < 4; i++) {
        acc0[i] = make_float4(0.f, 0.f, 0.f, 0.f);
        acc1[i] = make_float4(0.f, 0.f, 0.f, 0.f);
    }
#pragma unroll 4
    for (int k = 0; k < 128; ++k) {
        float4 b0 = *(const float4*)(W + k * FD + tx * 4);
        float4 b1 = *(const float4*)(W + k * FD + 64 + tx * 4);
#pragma unroll
        for (int i = 0; i < 4; i++) {
            float a = sX[ty * 4 + i][k];
            acc0[i].x += a * b0.x; acc0[i].y += a * b0.y;
            acc0[i].z += a * b0.z; acc0[i].w += a * b0.w;
            acc1[i].x += a * b1.x; acc1[i].y += a * b1.y;
            acc1[i].z += a * b1.z; acc1[i].w += a * b1.w;
        }
    }
#pragma unroll
    for (int i = 0; i < 4; i++) {
        int gr = row0 + ty * 4 + i;
        if (gr < n) {
            ushort4 o0, o1;
            o0.x = f2bf(acc0[i].x); o0.y = f2bf(acc0[i].y);
            o0.z = f2bf(acc0[i].z); o0.w = f2bf(acc0[i].w);
            o1.x = f2bf(acc1[i].x); o1.y = f2bf(acc1[i].y);
            o1.z = f2bf(acc1[i].z); o1.w = f2bf(acc1[i].w);
            *(ushort4*)(Fb + (size_t)gr * FD + tx * 4) = o0;
            *(ushort4*)(Fb + (size_t)gr * FD + 64 + tx * 4) = o1;
        }
    }
}

// ---------------- attention scores el/er from bf16 features (f32 math) ----------------

__global__ void k_scores(const unsigned short* __restrict__ Fb, const float* __restrict__ al,
                         const float* __restrict__ ar, float* __restrict__ el,
                         float* __restrict__ er) {
    int idx = blockIdx.x * 256 + threadIdx.x;
    if (idx >= NN * 4) return;
    int h = idx & 3;
    const uint4* f16 = (const uint4*)(Fb + (size_t)idx * 32);
    const float* a = al + h * 32;
    const float* b = ar + h * 32;
    float sl = 0.f, sr = 0.f;
#pragma unroll
    for (int i = 0; i < 4; i++) {
        uint4 u = f16[i];
        float f[8];
        f[0] = __uint_as_float(u.x << 16); f[1] = __uint_as_float(u.x & 0xffff0000u);
        f[2] = __uint_as_float(u.y << 16); f[3] = __uint_as_float(u.y & 0xffff0000u);
        f[4] = __uint_as_float(u.z << 16); f[5] = __uint_as_float(u.z & 0xffff0000u);
        f[6] = __uint_as_float(u.w << 16); f[7] = __uint_as_float(u.w & 0xffff0000u);
#pragma unroll
        for (int k2 = 0; k2 < 8; k2++) {
            sl = fmaf(f[k2], a[i * 8 + k2], sl);
            sr = fmaf(f[k2], b[i * 8 + k2], sr);
        }
    }
    el[idx] = sl;
    er[idx] = sr;
}

// ---------------- aggregation: one wave per dst node ----------------

__global__ __launch_bounds__(256) void k_agg(const unsigned short* __restrict__ Fb,
                                             const float* __restrict__ el,
                                             const float* __restrict__ er,
                                             const int* __restrict__ off,
                                             const int* __restrict__ ssrc,
                                             float* __restrict__ out) {
    int wave = threadIdx.x >> 6;
    int lane = threadIdx.x & 63;
    int d = blockIdx.x * 4 + wave;
    if (d >= NN) return;
    int start = off[d];
    int deg = off[d + 1] - start;
    float2 acc = make_float2(0.f, 0.f);
    if (deg > 0) {
        int h = lane & 3;
        int eloc = lane >> 2;
        float er_h = er[d * 4 + h];
        float m = -1e30f, s = 0.f;
        for (int base = 0; base < deg; base += 16) {
            int i = base + eloc;
            if (i < deg) {
                int sid = ssrc[start + i];
                float v = el[sid * 4 + h] + er_h;
                float e = v > 0.f ? v : 0.2f * v;
                if (e <= m) {
                    s += __expf(e - m);
                } else {
                    s = s * __expf(m - e) + 1.f;
                    m = e;
                }
            }
        }
        for (int o = 4; o < 64; o <<= 1) {
            float om = __shfl_xor(m, o);
            float os = __shfl_xor(s, o);
            float nm = fmaxf(m, om);
            s = s * __expf(m - nm) + os * __expf(om - nm);
            m = nm;
        }
        float inv_s = 1.f / s;
        int hsel = lane >> 4;  // head owning channels {2*lane, 2*lane+1}
        for (int base = 0; base < deg; base += 16) {
            int i = base + eloc;
            float a = 0.f;
            int sid = 0;  // invalid edges -> row 0 with alpha 0
            if (i < deg) {
                sid = ssrc[start + i];
                float v = el[sid * 4 + h] + er_h;
                float e2 = v > 0.f ? v : 0.2f * v;
                a = __expf(e2 - m) * inv_s;
            }
            int sids[16];
            float a16[16];
#pragma unroll
            for (int j = 0; j < 16; j++) {
                sids[j] = __builtin_amdgcn_readlane(sid, 4 * j);
                a16[j] = __shfl(a, 4 * j + hsel, 64);
            }
            unsigned int u[16];
#pragma unroll
            for (int j = 0; j < 16; j++) {
                u[j] = *(const unsigned int*)(Fb + (size_t)sids[j] * FD + lane * 2);
            }
#pragma unroll
            for (int j = 0; j < 16; j++) {
                float fx = __uint_as_float(u[j] << 16);
                float fy = __uint_as_float(u[j] & 0xffff0000u);
                acc.x = fmaf(a16[j], fx, acc.x);
                acc.y = fmaf(a16[j], fy, acc.y);
            }
        }
    }
    acc.x = fmaxf(acc.x, 0.f);  // relu
    acc.y = fmaxf(acc.y, 0.f);
    *(float2*)(out + (size_t)d * FD + lane * 2) = acc;
}

// ---------------- graph max-pool over nodes ----------------

__global__ void k_pool(const float* __restrict__ H, float* __restrict__ pooled) {
    int t = threadIdx.x;
    int c = t & 127;
    int seg = blockIdx.x * 2 + (t >> 7);
    const int NSEG = 256;
    int rpn = (NN + NSEG - 1) / NSEG;
    int r0 = seg * rpn;
    int r1 = min(NN, r0 + rpn);
    float m = 0.f;
    for (int r = r0; r < r1; ++r) m = fmaxf(m, H[(size_t)r * FD + c]);
    atomicMax((int*)&pooled[c], __float_as_int(m));
}

// ---------------- final FC + softmax ----------------

__global__ void k_final(const float* __restrict__ pooled, const float* __restrict__ Wfc,
                        const float* __restrict__ bfc, float* __restrict__ outp) {
    int lane = threadIdx.x;
    int j = lane & 7;
    int kk = lane >> 3;
    float partial = 0.f;
    for (int k = kk * 16; k < kk * 16 + 16; ++k) partial += pooled[k] * Wfc[k * 8 + j];
    for (int o = 8; o < 64; o <<= 1) partial += __shfl_xor(partial, o);
    float logit = partial + bfc[j];
    float mx = logit;
    for (int o = 1; o < 8; o <<= 1) mx = fmaxf(mx, __shfl_xor(mx, o));
    float ex = __expf(logit - mx);
    float sm = ex;
    for (int o = 1; o < 8; o <<= 1) sm += __shfl_xor(sm, o);
    if (lane < 8) outp[lane] = ex / sm;
}

// ---------------- launch ----------------

extern "C" void kernel_launch(void* const* d_in, const int* in_sizes, int n_in,
                              void* d_out, int out_size, void* d_ws, size_t ws_size,
                              hipStream_t stream) {
    const float* x   = (const float*)d_in[0];
    const int*   src = (const int*)d_in[1];
    const int*   dst = (const int*)d_in[2];
    const float* W1  = (const float*)d_in[3];
    const float* al1 = (const float*)d_in[4];
    const float* ar1 = (const float*)d_in[5];
    const float* W2  = (const float*)d_in[6];
    const float* al2 = (const float*)d_in[7];
    const float* ar2 = (const float*)d_in[8];
    const float* W3  = (const float*)d_in[9];
    const float* al3 = (const float*)d_in[10];
    const float* ar3 = (const float*)d_in[11];
    const float* Wfc = (const float*)d_in[12];
    const float* bfc = (const float*)d_in[13];
    float* out = (float*)d_out;

    char* p = (char*)d_ws;
    auto alloc = [&](size_t bytes) {
        char* r = p;
        p += (bytes + 255) & ~(size_t)255;
        return r;
    };
    unsigned short* Fb = (unsigned short*)alloc((size_t)NN * FD * 2);
    float* H      = (float*)alloc((size_t)NN * FD * 4);
    float* el     = (float*)alloc((size_t)NN * 4 * 4);
    float* er     = (float*)alloc((size_t)NN * 4 * 4);
    int*   off    = (int*)alloc((size_t)(NN + 1) * 4);
    int*   cnt    = (int*)alloc((size_t)NN * 4);
    int*   bsum   = (int*)alloc(128 * 4);
    int*   ssrc   = (int*)alloc((size_t)NE * 4);
    unsigned int* pairs = (unsigned int*)alloc((size_t)NE * 4);
    int*   gcur   = (int*)alloc((size_t)NB * 4);
    float* pooled = (float*)alloc(128 * 4);

    const int EB = (NE + 255) / 256;
    const int SB = (NN + 1023) / 1024;
    const int GB = (NN + 63) / 64;
    const int AB = (NN + 3) / 4;
    const int BB = (NE + CHUNK - 1) / CHUNK;  // 196

    hipMemsetAsync(cnt, 0, (size_t)NN * 4, stream);
    hipMemsetAsync(gcur, 0, (size_t)NB * 4, stream);
    hipMemsetAsync(pooled, 0, 128 * 4, stream);

    k_hist<<<EB, 256, 0, stream>>>(dst, cnt);
    k_scan1<<<SB, 256, 0, stream>>>(cnt, off, bsum);
    k_scan2<<<1, 64, 0, stream>>>(bsum, SB);
    k_add<<<(NN + 256) / 256, 256, 0, stream>>>(off, bsum);
    k_bucket<<<BB, 256, 0, stream>>>(src, dst, off, gcur, pairs);
    k_bsort<<<NB, 256, 0, stream>>>(pairs, off, ssrc);

    // layer 1
    k_gemm<<<GB, 256, 0, stream>>>(x, W1, Fb, NN);
    k_scores<<<(NN * 4 + 255) / 256, 256, 0, stream>>>(Fb, al1, ar1, el, er);
    k_agg<<<AB, 256, 0, stream>>>(Fb, el, er, off, ssrc, H);
    // layer 2
    k_gemm<<<GB, 256, 0, stream>>>(H, W2, Fb, NN);
    k_scores<<<(NN * 4 + 255) / 256, 256, 0, stream>>>(Fb, al2, ar2, el, er);
    k_agg<<<AB, 256, 0, stream>>>(Fb, el, er, off, ssrc, H);
    // layer 3
    k_gemm<<<GB, 256, 0, stream>>>(H, W3, Fb, NN);
    k_scores<<<(NN * 4 + 255) / 256, 256, 0, stream>>>(Fb, al3, ar3, el, er);
    k_agg<<<AB, 256, 0, stream>>>(Fb, el, er, off, ssrc, H);

    k_pool<<<128, 256, 0, stream>>>(H, pooled);
    k_final<<<1, 64, 0, stream>>>(pooled, Wfc, bfc, out);
}

// Round 5
// 714.602 us; speedup vs baseline: 1.6875x; 1.0873x over previous
//
#include <hip/hip_runtime.h>

#define NN 100000   // nodes
#define NE 1600000  // edges
#define FD 128      // feature dim (4 heads x 32 ch)
#define NB 391      // ceil(NN/256) dst-buckets
#define CHUNK 8192  // edges per k_bucket block

typedef __attribute__((ext_vector_type(8))) short bf16x8;
typedef __attribute__((ext_vector_type(4))) float f32x4;

union B8 { bf16x8 v; unsigned int u[4]; };

// ---------------- helpers ----------------

__device__ __forceinline__ unsigned short f2bf(float x) {
    unsigned int u = __float_as_uint(x);
    u += 0x7fffu + ((u >> 16) & 1u);   // round-to-nearest-even
    return (unsigned short)(u >> 16);
}

// pack top-16s of two floats (truncation bf16): result = (hi16(b)<<16) | hi16(a)
__device__ __forceinline__ unsigned int pkhi(unsigned int ua, unsigned int ub) {
    return __builtin_amdgcn_perm(ub, ua, 0x07060302);
}

// truncation hi/lo split of 8 f32 -> bf16x8 hi, lo.  x ~= hi + lo to ~2^-14 rel.
__device__ __forceinline__ void split8(const float4& x0, const float4& x1,
                                       bf16x8& hi, bf16x8& lo) {
    float f[8] = {x0.x, x0.y, x0.z, x0.w, x1.x, x1.y, x1.z, x1.w};
    B8 H, L;
#pragma unroll
    for (int i = 0; i < 4; i++) {
        unsigned int ua = __float_as_uint(f[2 * i]);
        unsigned int ub = __float_as_uint(f[2 * i + 1]);
        H.u[i] = pkhi(ua, ub);
        float ra = f[2 * i]     - __uint_as_float(ua & 0xffff0000u);
        float rb = f[2 * i + 1] - __uint_as_float(ub & 0xffff0000u);
        L.u[i] = pkhi(__float_as_uint(ra), __float_as_uint(rb));
    }
    hi = H.v; lo = L.v;
}

// ---------------- per-node degree histogram + scan -> CSR offsets ----------------

__global__ void k_hist(const int* __restrict__ dst, int* __restrict__ cnt) {
    int e = blockIdx.x * 256 + threadIdx.x;
    if (e < NE) atomicAdd(&cnt[dst[e]], 1);
}

__global__ void k_scan1(const int* __restrict__ cnt, int* __restrict__ off, int* __restrict__ bsum) {
    __shared__ int sh[256];
    int t = threadIdx.x;
    int base = blockIdx.x * 1024 + t * 4;
    int v0 = (base + 0 < NN) ? cnt[base + 0] : 0;
    int v1 = (base + 1 < NN) ? cnt[base + 1] : 0;
    int v2 = (base + 2 < NN) ? cnt[base + 2] : 0;
    int v3 = (base + 3 < NN) ? cnt[base + 3] : 0;
    int tsum = v0 + v1 + v2 + v3;
    sh[t] = tsum;
    __syncthreads();
    for (int o = 1; o < 256; o <<= 1) {
        int x = (t >= o) ? sh[t - o] : 0;
        __syncthreads();
        sh[t] += x;
        __syncthreads();
    }
    int p = sh[t] - tsum;
    if (t == 255) bsum[blockIdx.x] = sh[255];
    if (base + 0 < NN) { off[base + 0] = p; p += v0; }
    if (base + 1 < NN) { off[base + 1] = p; p += v1; }
    if (base + 2 < NN) { off[base + 2] = p; p += v2; }
    if (base + 3 < NN) { off[base + 3] = p; p += v3; }
}

__global__ void k_scan2(int* bsum, int nb) {
    if (threadIdx.x == 0) {
        int run = 0;
        for (int i = 0; i < nb; i++) { int v = bsum[i]; bsum[i] = run; run += v; }
    }
}

__global__ void k_add(int* off, const int* __restrict__ bsum) {
    int i = blockIdx.x * 256 + threadIdx.x;
    if (i < NN) off[i] += bsum[i >> 10];
    else if (i == NN) off[i] = NE;
}

// ---------------- phase A: bucket edges by dst>>8 into CSR bucket regions ----------------

__global__ __launch_bounds__(256) void k_bucket(const int* __restrict__ src,
                                                const int* __restrict__ dst,
                                                const int* __restrict__ off,
                                                int* __restrict__ gcur,
                                                unsigned int* __restrict__ pairs) {
    __shared__ int scnt[NB];
    __shared__ int sbase[NB];
    int t = threadIdx.x;
    for (int i = t; i < NB; i += 256) scnt[i] = 0;
    __syncthreads();
    int e0 = blockIdx.x * CHUNK;
    int e1 = min(e0 + CHUNK, NE);
    for (int i = e0 + t; i < e1; i += 256) {
        atomicAdd(&scnt[dst[i] >> 8], 1);
    }
    __syncthreads();
    for (int i = t; i < NB; i += 256) {
        int c = scnt[i];
        sbase[i] = (c > 0) ? (off[i << 8] + atomicAdd(&gcur[i], c)) : 0;
        scnt[i] = 0;  // reuse as local cursor
    }
    __syncthreads();
    for (int i = e0 + t; i < e1; i += 256) {
        int d = dst[i];
        int b = d >> 8;
        int r = atomicAdd(&scnt[b], 1);
        pairs[sbase[b] + r] = (unsigned int)src[i] | ((unsigned int)(d & 255) << 17);
    }
}

// ---------------- phase B: within-bucket counting sort -> ssrc ----------------

__global__ __launch_bounds__(256) void k_bsort(const unsigned int* __restrict__ pairs,
                                               const int* __restrict__ off,
                                               int* __restrict__ ssrc) {
    __shared__ int cur[256];
    int t = threadIdx.x;
    int b = blockIdx.x;
    int nstart = b << 8;
    cur[t] = off[min(nstart + t, NN)];
    __syncthreads();
    int estart = off[nstart];
    int eend = off[min(nstart + 256, NN)];
    for (int i = estart + t; i < eend; i += 256) {
        unsigned int p = pairs[i];
        int ldst = (p >> 17) & 255;
        int pos = atomicAdd(&cur[ldst], 1);
        ssrc[pos] = (int)(p & 0x1ffffu);
    }
}

// ---------------- W pre-split: Wt_hi/Wt_lo[n][k] (transposed bf16 hi/lo) ----------------

__global__ void k_wsplit(const float* __restrict__ W, unsigned short* __restrict__ Wth,
                         unsigned short* __restrict__ Wtl) {
    int tid = blockIdx.x * 256 + threadIdx.x;  // 16384 = 128x128
    int n = tid >> 7, k = tid & 127;
    float w = W[k * 128 + n];
    unsigned short h = f2bf(w);
    float res = w - __uint_as_float((unsigned int)h << 16);
    Wth[tid] = h;
    Wtl[tid] = f2bf(res);
}

// ---------------- MFMA GEMM: Fb[n,128](bf16) = A[n,128](f32) @ W ----------------
// hi/lo bf16 split on both operands (3 MFMA products) ~= f32 accuracy.
// Tile: 128 rows/block, 4 waves x 32 rows. B-fragments from global (L1/L2-hot).

__global__ __launch_bounds__(256) void k_gemm(const float* __restrict__ A,
                                              const unsigned short* __restrict__ Wth,
                                              const unsigned short* __restrict__ Wtl,
                                              unsigned short* __restrict__ Fb, int nrows) {
    int t = threadIdx.x;
    int wave = t >> 6, lane = t & 63;
    int r = lane & 15, q = lane >> 4;
    int row0 = blockIdx.x * 128 + wave * 32;
    int rg0 = row0 + r, rg1 = row0 + 16 + r;

    f32x4 acc[2][8];
#pragma unroll
    for (int g = 0; g < 2; g++)
#pragma unroll
        for (int nt = 0; nt < 8; nt++) acc[g][nt] = (f32x4){0.f, 0.f, 0.f, 0.f};

#pragma unroll
    for (int ks = 0; ks < 4; ks++) {
        int k0 = ks * 32 + q * 8;
        float4 z = make_float4(0.f, 0.f, 0.f, 0.f);
        float4 a0 = z, a1 = z, b0 = z, b1 = z;
        if (rg0 < nrows) {
            const float* pa = A + (size_t)rg0 * FD + k0;
            a0 = *(const float4*)pa;
            a1 = *(const float4*)(pa + 4);
        }
        if (rg1 < nrows) {
            const float* pb = A + (size_t)rg1 * FD + k0;
            b0 = *(const float4*)pb;
            b1 = *(const float4*)(pb + 4);
        }
        bf16x8 ah0, al0, ah1, al1;
        split8(a0, a1, ah0, al0);
        split8(b0, b1, ah1, al1);
#pragma unroll
        for (int nt = 0; nt < 8; nt++) {
            int wo = ((nt * 16 + r) << 7) + k0;
            bf16x8 bh = *(const bf16x8*)(Wth + wo);
            bf16x8 bl = *(const bf16x8*)(Wtl + wo);
            acc[0][nt] = __builtin_amdgcn_mfma_f32_16x16x32_bf16(ah0, bh, acc[0][nt], 0, 0, 0);
            acc[0][nt] = __builtin_amdgcn_mfma_f32_16x16x32_bf16(al0, bh, acc[0][nt], 0, 0, 0);
            acc[0][nt] = __builtin_amdgcn_mfma_f32_16x16x32_bf16(ah0, bl, acc[0][nt], 0, 0, 0);
            acc[1][nt] = __builtin_amdgcn_mfma_f32_16x16x32_bf16(ah1, bh, acc[1][nt], 0, 0, 0);
            acc[1][nt] = __builtin_amdgcn_mfma_f32_16x16x32_bf16(al1, bh, acc[1][nt], 0, 0, 0);
            acc[1][nt] = __builtin_amdgcn_mfma_f32_16x16x32_bf16(ah1, bl, acc[1][nt], 0, 0, 0);
        }
    }
    // C layout: row = q*4 + i (within 16-row group), col = nt*16 + r
#pragma unroll
    for (int g = 0; g < 2; g++) {
#pragma unroll
        for (int i = 0; i < 4; i++) {
            int row = row0 + g * 16 + q * 4 + i;
            if (row < nrows) {
#pragma unroll
                for (int nt = 0; nt < 8; nt++) {
                    Fb[(size_t)row * FD + nt * 16 + r] = f2bf(acc[g][nt][i]);
                }
            }
        }
    }
}

// ---------------- attention scores el/er from bf16 features (f32 math) ----------------

__global__ void k_scores(const unsigned short* __restrict__ Fb, const float* __restrict__ al,
                         const float* __restrict__ ar, float* __restrict__ el,
                         float* __restrict__ er) {
    int idx = blockIdx.x * 256 + threadIdx.x;
    if (idx >= NN * 4) return;
    int h = idx & 3;
    const uint4* f16 = (const uint4*)(Fb + (size_t)idx * 32);
    const float* a = al + h * 32;
    const float* b = ar + h * 32;
    float sl = 0.f, sr = 0.f;
#pragma unroll
    for (int i = 0; i < 4; i++) {
        uint4 u = f16[i];
        float f[8];
        f[0] = __uint_as_float(u.x << 16); f[1] = __uint_as_float(u.x & 0xffff0000u);
        f[2] = __uint_as_float(u.y << 16); f[3] = __uint_as_float(u.y & 0xffff0000u);
        f[4] = __uint_as_float(u.z << 16); f[5] = __uint_as_float(u.z & 0xffff0000u);
        f[6] = __uint_as_float(u.w << 16); f[7] = __uint_as_float(u.w & 0xffff0000u);
#pragma unroll
        for (int k2 = 0; k2 < 8; k2++) {
            sl = fmaf(f[k2], a[i * 8 + k2], sl);
            sr = fmaf(f[k2], b[i * 8 + k2], sr);
        }
    }
    el[idx] = sl;
    er[idx] = sr;
}

// ---------------- aggregation: one wave per dst node ----------------

__global__ __launch_bounds__(256) void k_agg(const unsigned short* __restrict__ Fb,
                                             const float* __restrict__ el,
                                             const float* __restrict__ er,
                                             const int* __restrict__ off,
                                             const int* __restrict__ ssrc,
                                             float* __restrict__ out) {
    int wave = threadIdx.x >> 6;
    int lane = threadIdx.x & 63;
    int d = blockIdx.x * 4 + wave;
    if (d >= NN) return;
    int start = off[d];
    int deg = off[d + 1] - start;
    float2 acc = make_float2(0.f, 0.f);
    if (deg > 0) {
        int h = lane & 3;
        int eloc = lane >> 2;
        float er_h = er[d * 4 + h];
        float m = -1e30f, s = 0.f;
        for (int base = 0; base < deg; base += 16) {
            int i = base + eloc;
            if (i < deg) {
                int sid = ssrc[start + i];
                float v = el[sid * 4 + h] + er_h;
                float e = v > 0.f ? v : 0.2f * v;
                if (e <= m) {
                    s += __expf(e - m);
                } else {
                    s = s * __expf(m - e) + 1.f;
                    m = e;
                }
            }
        }
        for (int o = 4; o < 64; o <<= 1) {
            float om = __shfl_xor(m, o);
            float os = __shfl_xor(s, o);
            float nm = fmaxf(m, om);
            s = s * __expf(m - nm) + os * __expf(om - nm);
            m = nm;
        }
        float inv_s = 1.f / s;
        int hsel = lane >> 4;
        for (int base = 0; base < deg; base += 16) {
            int i = base + eloc;
            float a = 0.f;
            int sid = 0;
            if (i < deg) {
                sid = ssrc[start + i];
                float v = el[sid * 4 + h] + er_h;
                float e2 = v > 0.f ? v : 0.2f * v;
                a = __expf(e2 - m) * inv_s;
            }
            int sids[16];
            float a16[16];
#pragma unroll
            for (int j = 0; j < 16; j++) {
                sids[j] = __builtin_amdgcn_readlane(sid, 4 * j);
                a16[j] = __shfl(a, 4 * j + hsel, 64);
            }
            unsigned int u[16];
#pragma unroll
            for (int j = 0; j < 16; j++) {
                u[j] = *(const unsigned int*)(Fb + (size_t)sids[j] * FD + lane * 2);
            }
#pragma unroll
            for (int j = 0; j < 16; j++) {
                float fx = __uint_as_float(u[j] << 16);
                float fy = __uint_as_float(u[j] & 0xffff0000u);
                acc.x = fmaf(a16[j], fx, acc.x);
                acc.y = fmaf(a16[j], fy, acc.y);
            }
        }
    }
    acc.x = fmaxf(acc.x, 0.f);
    acc.y = fmaxf(acc.y, 0.f);
    *(float2*)(out + (size_t)d * FD + lane * 2) = acc;
}

// ---------------- graph max-pool over nodes ----------------

__global__ void k_pool(const float* __restrict__ H, float* __restrict__ pooled) {
    int t = threadIdx.x;
    int c = t & 127;
    int seg = blockIdx.x * 2 + (t >> 7);
    const int NSEG = 256;
    int rpn = (NN + NSEG - 1) / NSEG;
    int r0 = seg * rpn;
    int r1 = min(NN, r0 + rpn);
    float m = 0.f;
    for (int r = r0; r < r1; ++r) m = fmaxf(m, H[(size_t)r * FD + c]);
    atomicMax((int*)&pooled[c], __float_as_int(m));
}

// ---------------- final FC + softmax ----------------

__global__ void k_final(const float* __restrict__ pooled, const float* __restrict__ Wfc,
                        const float* __restrict__ bfc, float* __restrict__ outp) {
    int lane = threadIdx.x;
    int j = lane & 7;
    int kk = lane >> 3;
    float partial = 0.f;
    for (int k = kk * 16; k < kk * 16 + 16; ++k) partial += pooled[k] * Wfc[k * 8 + j];
    for (int o = 8; o < 64; o <<= 1) partial += __shfl_xor(partial, o);
    float logit = partial + bfc[j];
    float mx = logit;
    for (int o = 1; o < 8; o <<= 1) mx = fmaxf(mx, __shfl_xor(mx, o));
    float ex = __expf(logit - mx);
    float sm = ex;
    for (int o = 1; o < 8; o <<= 1) sm += __shfl_xor(sm, o);
    if (lane < 8) outp[lane] = ex / sm;
}

// ---------------- launch ----------------

extern "C" void kernel_launch(void* const* d_in, const int* in_sizes, int n_in,
                              void* d_out, int out_size, void* d_ws, size_t ws_size,
                              hipStream_t stream) {
    const float* x   = (const float*)d_in[0];
    const int*   src = (const int*)d_in[1];
    const int*   dst = (const int*)d_in[2];
    const float* W1  = (const float*)d_in[3];
    const float* al1 = (const float*)d_in[4];
    const float* ar1 = (const float*)d_in[5];
    const float* W2  = (const float*)d_in[6];
    const float* al2 = (const float*)d_in[7];
    const float* ar2 = (const float*)d_in[8];
    const float* W3  = (const float*)d_in[9];
    const float* al3 = (const float*)d_in[10];
    const float* ar3 = (const float*)d_in[11];
    const float* Wfc = (const float*)d_in[12];
    const float* bfc = (const float*)d_in[13];
    float* out = (float*)d_out;

    char* p = (char*)d_ws;
    auto alloc = [&](size_t bytes) {
        char* r = p;
        p += (bytes + 255) & ~(size_t)255;
        return r;
    };
    unsigned short* Fb = (unsigned short*)alloc((size_t)NN * FD * 2);
    float* H      = (float*)alloc((size_t)NN * FD * 4);
    float* el     = (float*)alloc((size_t)NN * 4 * 4);
    float* er     = (float*)alloc((size_t)NN * 4 * 4);
    int*   off    = (int*)alloc((size_t)(NN + 1) * 4);
    int*   cnt    = (int*)alloc((size_t)NN * 4);
    int*   bsum   = (int*)alloc(128 * 4);
    int*   ssrc   = (int*)alloc((size_t)NE * 4);
    unsigned int* pairs = (unsigned int*)alloc((size_t)NE * 4);
    int*   gcur   = (int*)alloc((size_t)NB * 4);
    float* pooled = (float*)alloc(128 * 4);
    unsigned short* Wth1 = (unsigned short*)alloc(16384 * 2);
    unsigned short* Wtl1 = (unsigned short*)alloc(16384 * 2);
    unsigned short* Wth2 = (unsigned short*)alloc(16384 * 2);
    unsigned short* Wtl2 = (unsigned short*)alloc(16384 * 2);
    unsigned short* Wth3 = (unsigned short*)alloc(16384 * 2);
    unsigned short* Wtl3 = (unsigned short*)alloc(16384 * 2);

    const int EB = (NE + 255) / 256;
    const int SB = (NN + 1023) / 1024;
    const int GB = (NN + 127) / 128;          // 782 MFMA-GEMM blocks
    const int AB = (NN + 3) / 4;
    const int BB = (NE + CHUNK - 1) / CHUNK;  // 196

    hipMemsetAsync(cnt, 0, (size_t)NN * 4, stream);
    hipMemsetAsync(gcur, 0, (size_t)NB * 4, stream);
    hipMemsetAsync(pooled, 0, 128 * 4, stream);

    k_wsplit<<<64, 256, 0, stream>>>(W1, Wth1, Wtl1);
    k_wsplit<<<64, 256, 0, stream>>>(W2, Wth2, Wtl2);
    k_wsplit<<<64, 256, 0, stream>>>(W3, Wth3, Wtl3);

    k_hist<<<EB, 256, 0, stream>>>(dst, cnt);
    k_scan1<<<SB, 256, 0, stream>>>(cnt, off, bsum);
    k_scan2<<<1, 64, 0, stream>>>(bsum, SB);
    k_add<<<(NN + 256) / 256, 256, 0, stream>>>(off, bsum);
    k_bucket<<<BB, 256, 0, stream>>>(src, dst, off, gcur, pairs);
    k_bsort<<<NB, 256, 0, stream>>>(pairs, off, ssrc);

    // layer 1
    k_gemm<<<GB, 256, 0, stream>>>(x, Wth1, Wtl1, Fb, NN);
    k_scores<<<(NN * 4 + 255) / 256, 256, 0, stream>>>(Fb, al1, ar1, el, er);
    k_agg<<<AB, 256, 0, stream>>>(Fb, el, er, off, ssrc, H);
    // layer 2
    k_gemm<<<GB, 256, 0, stream>>>(H, Wth2, Wtl2, Fb, NN);
    k_scores<<<(NN * 4 + 255) / 256, 256, 0, stream>>>(Fb, al2, ar2, el, er);
    k_agg<<<AB, 256, 0, stream>>>(Fb, el, er, off, ssrc, H);
    // layer 3
    k_gemm<<<GB, 256, 0, stream>>>(H, Wth3, Wtl3, Fb, NN);
    k_scores<<<(NN * 4 + 255) / 256, 256, 0, stream>>>(Fb, al3, ar3, el, er);
    k_agg<<<AB, 256, 0, stream>>>(Fb, el, er, off, ssrc, H);

    k_pool<<<128, 256, 0, stream>>>(H, pooled);
    k_final<<<1, 64, 0, stream>>>(pooled, Wfc, bfc, out);
}

// Round 6
// 685.479 us; speedup vs baseline: 1.7592x; 1.0425x over previous
//
#include <hip/hip_runtime.h>

#define NN 100000   // nodes
#define NE 1600000  // edges
#define FD 128      // feature dim (4 heads x 32 ch)
#define NB 391      // ceil(NN/256) dst-buckets
#define CHUNK 8192  // edges per k_bucket block

typedef __attribute__((ext_vector_type(8))) short bf16x8;
typedef __attribute__((ext_vector_type(4))) float f32x4;

union B8 { bf16x8 v; unsigned int u[4]; };

// ---------------- helpers ----------------

__device__ __forceinline__ unsigned short f2bf(float x) {
    unsigned int u = __float_as_uint(x);
    u += 0x7fffu + ((u >> 16) & 1u);   // round-to-nearest-even
    return (unsigned short)(u >> 16);
}

__device__ __forceinline__ unsigned int pkhi(unsigned int ua, unsigned int ub) {
    return __builtin_amdgcn_perm(ub, ua, 0x07060302);
}

// truncation hi/lo split of 8 f32 -> bf16x8 hi, lo.  x ~= hi + lo to ~2^-14 rel.
__device__ __forceinline__ void split8(const float4& x0, const float4& x1,
                                       bf16x8& hi, bf16x8& lo) {
    float f[8] = {x0.x, x0.y, x0.z, x0.w, x1.x, x1.y, x1.z, x1.w};
    B8 H, L;
#pragma unroll
    for (int i = 0; i < 4; i++) {
        unsigned int ua = __float_as_uint(f[2 * i]);
        unsigned int ub = __float_as_uint(f[2 * i + 1]);
        H.u[i] = pkhi(ua, ub);
        float ra = f[2 * i]     - __uint_as_float(ua & 0xffff0000u);
        float rb = f[2 * i + 1] - __uint_as_float(ub & 0xffff0000u);
        L.u[i] = pkhi(__float_as_uint(ra), __float_as_uint(rb));
    }
    hi = H.v; lo = L.v;
}

// ---------------- per-node degree histogram + scan -> CSR offsets ----------------

__global__ void k_hist(const int* __restrict__ dst, int* __restrict__ cnt) {
    int e = blockIdx.x * 256 + threadIdx.x;
    if (e < NE) atomicAdd(&cnt[dst[e]], 1);
}

__global__ void k_scan1(const int* __restrict__ cnt, int* __restrict__ off, int* __restrict__ bsum) {
    __shared__ int sh[256];
    int t = threadIdx.x;
    int base = blockIdx.x * 1024 + t * 4;
    int v0 = (base + 0 < NN) ? cnt[base + 0] : 0;
    int v1 = (base + 1 < NN) ? cnt[base + 1] : 0;
    int v2 = (base + 2 < NN) ? cnt[base + 2] : 0;
    int v3 = (base + 3 < NN) ? cnt[base + 3] : 0;
    int tsum = v0 + v1 + v2 + v3;
    sh[t] = tsum;
    __syncthreads();
    for (int o = 1; o < 256; o <<= 1) {
        int x = (t >= o) ? sh[t - o] : 0;
        __syncthreads();
        sh[t] += x;
        __syncthreads();
    }
    int p = sh[t] - tsum;
    if (t == 255) bsum[blockIdx.x] = sh[255];
    if (base + 0 < NN) { off[base + 0] = p; p += v0; }
    if (base + 1 < NN) { off[base + 1] = p; p += v1; }
    if (base + 2 < NN) { off[base + 2] = p; p += v2; }
    if (base + 3 < NN) { off[base + 3] = p; p += v3; }
}

__global__ void k_scan2(int* bsum, int nb) {
    if (threadIdx.x == 0) {
        int run = 0;
        for (int i = 0; i < nb; i++) { int v = bsum[i]; bsum[i] = run; run += v; }
    }
}

__global__ void k_add(int* off, const int* __restrict__ bsum) {
    int i = blockIdx.x * 256 + threadIdx.x;
    if (i < NN) off[i] += bsum[i >> 10];
    else if (i == NN) off[i] = NE;
}

// ---------------- phase A: bucket edges by dst>>8 into CSR bucket regions ----------------

__global__ __launch_bounds__(256) void k_bucket(const int* __restrict__ src,
                                                const int* __restrict__ dst,
                                                const int* __restrict__ off,
                                                int* __restrict__ gcur,
                                                unsigned int* __restrict__ pairs) {
    __shared__ int scnt[NB];
    __shared__ int sbase[NB];
    int t = threadIdx.x;
    for (int i = t; i < NB; i += 256) scnt[i] = 0;
    __syncthreads();
    int e0 = blockIdx.x * CHUNK;
    int e1 = min(e0 + CHUNK, NE);
    for (int i = e0 + t; i < e1; i += 256) {
        atomicAdd(&scnt[dst[i] >> 8], 1);
    }
    __syncthreads();
    for (int i = t; i < NB; i += 256) {
        int c = scnt[i];
        sbase[i] = (c > 0) ? (off[i << 8] + atomicAdd(&gcur[i], c)) : 0;
        scnt[i] = 0;  // reuse as local cursor
    }
    __syncthreads();
    for (int i = e0 + t; i < e1; i += 256) {
        int d = dst[i];
        int b = d >> 8;
        int r = atomicAdd(&scnt[b], 1);
        pairs[sbase[b] + r] = (unsigned int)src[i] | ((unsigned int)(d & 255) << 17);
    }
}

// ---------------- phase B: within-bucket counting sort -> ssrc ----------------

__global__ __launch_bounds__(256) void k_bsort(const unsigned int* __restrict__ pairs,
                                               const int* __restrict__ off,
                                               int* __restrict__ ssrc) {
    __shared__ int cur[256];
    int t = threadIdx.x;
    int b = blockIdx.x;
    int nstart = b << 8;
    cur[t] = off[min(nstart + t, NN)];
    __syncthreads();
    int estart = off[nstart];
    int eend = off[min(nstart + 256, NN)];
    for (int i = estart + t; i < eend; i += 256) {
        unsigned int p = pairs[i];
        int ldst = (p >> 17) & 255;
        int pos = atomicAdd(&cur[ldst], 1);
        ssrc[pos] = (int)(p & 0x1ffffu);
    }
}

// ---------------- W pre-split: Wt_hi/Wt_lo[n][k] (transposed bf16 hi/lo) ----------------

__global__ void k_wsplit(const float* __restrict__ W, unsigned short* __restrict__ Wth,
                         unsigned short* __restrict__ Wtl) {
    int tid = blockIdx.x * 256 + threadIdx.x;  // 16384 = 128x128
    int n = tid >> 7, k = tid & 127;
    float w = W[k * 128 + n];
    unsigned short h = f2bf(w);
    float res = w - __uint_as_float((unsigned int)h << 16);
    Wth[tid] = h;
    Wtl[tid] = f2bf(res);
}

// ---------------- MFMA GEMM (layer 1): A f32, hi/lo split both sides ----------------

__global__ __launch_bounds__(256) void k_gemm_f32(const float* __restrict__ A,
                                                  const unsigned short* __restrict__ Wth,
                                                  const unsigned short* __restrict__ Wtl,
                                                  unsigned short* __restrict__ Fb, int nrows) {
    int t = threadIdx.x;
    int wave = t >> 6, lane = t & 63;
    int r = lane & 15, q = lane >> 4;
    int row0 = blockIdx.x * 128 + wave * 32;
    int rg0 = row0 + r, rg1 = row0 + 16 + r;

    f32x4 acc[2][8];
#pragma unroll
    for (int g = 0; g < 2; g++)
#pragma unroll
        for (int nt = 0; nt < 8; nt++) acc[g][nt] = (f32x4){0.f, 0.f, 0.f, 0.f};

#pragma unroll
    for (int ks = 0; ks < 4; ks++) {
        int k0 = ks * 32 + q * 8;
        float4 z = make_float4(0.f, 0.f, 0.f, 0.f);
        float4 a0 = z, a1 = z, b0 = z, b1 = z;
        if (rg0 < nrows) {
            const float* pa = A + (size_t)rg0 * FD + k0;
            a0 = *(const float4*)pa;
            a1 = *(const float4*)(pa + 4);
        }
        if (rg1 < nrows) {
            const float* pb = A + (size_t)rg1 * FD + k0;
            b0 = *(const float4*)pb;
            b1 = *(const float4*)(pb + 4);
        }
        bf16x8 ah0, al0, ah1, al1;
        split8(a0, a1, ah0, al0);
        split8(b0, b1, ah1, al1);
#pragma unroll
        for (int nt = 0; nt < 8; nt++) {
            int wo = ((nt * 16 + r) << 7) + k0;
            bf16x8 bh = *(const bf16x8*)(Wth + wo);
            bf16x8 bl = *(const bf16x8*)(Wtl + wo);
            acc[0][nt] = __builtin_amdgcn_mfma_f32_16x16x32_bf16(ah0, bh, acc[0][nt], 0, 0, 0);
            acc[0][nt] = __builtin_amdgcn_mfma_f32_16x16x32_bf16(al0, bh, acc[0][nt], 0, 0, 0);
            acc[0][nt] = __builtin_amdgcn_mfma_f32_16x16x32_bf16(ah0, bl, acc[0][nt], 0, 0, 0);
            acc[1][nt] = __builtin_amdgcn_mfma_f32_16x16x32_bf16(ah1, bh, acc[1][nt], 0, 0, 0);
            acc[1][nt] = __builtin_amdgcn_mfma_f32_16x16x32_bf16(al1, bh, acc[1][nt], 0, 0, 0);
            acc[1][nt] = __builtin_amdgcn_mfma_f32_16x16x32_bf16(ah1, bl, acc[1][nt], 0, 0, 0);
        }
    }
#pragma unroll
    for (int g = 0; g < 2; g++) {
#pragma unroll
        for (int i = 0; i < 4; i++) {
            int row = row0 + g * 16 + q * 4 + i;
            if (row < nrows) {
#pragma unroll
                for (int nt = 0; nt < 8; nt++) {
                    Fb[(size_t)row * FD + nt * 16 + r] = f2bf(acc[g][nt][i]);
                }
            }
        }
    }
}

// ---------------- MFMA GEMM (layers 2,3): A bf16, W hi/lo -> 2 MFMAs ----------------

__global__ __launch_bounds__(256) void k_gemm_bf(const unsigned short* __restrict__ A,
                                                 const unsigned short* __restrict__ Wth,
                                                 const unsigned short* __restrict__ Wtl,
                                                 unsigned short* __restrict__ Fb, int nrows) {
    int t = threadIdx.x;
    int wave = t >> 6, lane = t & 63;
    int r = lane & 15, q = lane >> 4;
    int row0 = blockIdx.x * 128 + wave * 32;
    int rg0 = row0 + r, rg1 = row0 + 16 + r;

    f32x4 acc[2][8];
#pragma unroll
    for (int g = 0; g < 2; g++)
#pragma unroll
        for (int nt = 0; nt < 8; nt++) acc[g][nt] = (f32x4){0.f, 0.f, 0.f, 0.f};

#pragma unroll
    for (int ks = 0; ks < 4; ks++) {
        int k0 = ks * 32 + q * 8;
        bf16x8 a0 = {0, 0, 0, 0, 0, 0, 0, 0};
        bf16x8 a1 = {0, 0, 0, 0, 0, 0, 0, 0};
        if (rg0 < nrows) a0 = *(const bf16x8*)(A + (size_t)rg0 * FD + k0);
        if (rg1 < nrows) a1 = *(const bf16x8*)(A + (size_t)rg1 * FD + k0);
#pragma unroll
        for (int nt = 0; nt < 8; nt++) {
            int wo = ((nt * 16 + r) << 7) + k0;
            bf16x8 bh = *(const bf16x8*)(Wth + wo);
            bf16x8 bl = *(const bf16x8*)(Wtl + wo);
            acc[0][nt] = __builtin_amdgcn_mfma_f32_16x16x32_bf16(a0, bh, acc[0][nt], 0, 0, 0);
            acc[0][nt] = __builtin_amdgcn_mfma_f32_16x16x32_bf16(a0, bl, acc[0][nt], 0, 0, 0);
            acc[1][nt] = __builtin_amdgcn_mfma_f32_16x16x32_bf16(a1, bh, acc[1][nt], 0, 0, 0);
            acc[1][nt] = __builtin_amdgcn_mfma_f32_16x16x32_bf16(a1, bl, acc[1][nt], 0, 0, 0);
        }
    }
#pragma unroll
    for (int g = 0; g < 2; g++) {
#pragma unroll
        for (int i = 0; i < 4; i++) {
            int row = row0 + g * 16 + q * 4 + i;
            if (row < nrows) {
#pragma unroll
                for (int nt = 0; nt < 8; nt++) {
                    Fb[(size_t)row * FD + nt * 16 + r] = f2bf(acc[g][nt][i]);
                }
            }
        }
    }
}

// ---------------- attention scores el/er from bf16 features (f32 math) ----------------

__global__ void k_scores(const unsigned short* __restrict__ Fb, const float* __restrict__ al,
                         const float* __restrict__ ar, float* __restrict__ el,
                         float* __restrict__ er) {
    int idx = blockIdx.x * 256 + threadIdx.x;
    if (idx >= NN * 4) return;
    int h = idx & 3;
    const uint4* f16 = (const uint4*)(Fb + (size_t)idx * 32);
    const float* a = al + h * 32;
    const float* b = ar + h * 32;
    float sl = 0.f, sr = 0.f;
#pragma unroll
    for (int i = 0; i < 4; i++) {
        uint4 u = f16[i];
        float f[8];
        f[0] = __uint_as_float(u.x << 16); f[1] = __uint_as_float(u.x & 0xffff0000u);
        f[2] = __uint_as_float(u.y << 16); f[3] = __uint_as_float(u.y & 0xffff0000u);
        f[4] = __uint_as_float(u.z << 16); f[5] = __uint_as_float(u.z & 0xffff0000u);
        f[6] = __uint_as_float(u.w << 16); f[7] = __uint_as_float(u.w & 0xffff0000u);
#pragma unroll
        for (int k2 = 0; k2 < 8; k2++) {
            sl = fmaf(f[k2], a[i * 8 + k2], sl);
            sr = fmaf(f[k2], b[i * 8 + k2], sr);
        }
    }
    el[idx] = sl;
    er[idx] = sr;
}

// ---------------- aggregation: one wave per dst node ----------------
// pass1: max-only reduction, (sid,e) register-cached for deg<=64
// pass2: one exp per edge feeding both denominator and weight; normalize at end.
// BF16OUT=1 -> packed bf16 rows (layers 1,2); 0 -> f32 rows (layer 3).

template <int BF16OUT>
__global__ __launch_bounds__(256) void k_agg(const unsigned short* __restrict__ Fb,
                                             const float* __restrict__ el,
                                             const float* __restrict__ er,
                                             const int* __restrict__ off,
                                             const int* __restrict__ ssrc,
                                             void* __restrict__ outv) {
    int wave = threadIdx.x >> 6;
    int lane = threadIdx.x & 63;
    int d = blockIdx.x * 4 + wave;
    if (d >= NN) return;
    int start = off[d];
    int deg = off[d + 1] - start;
    float2 acc = make_float2(0.f, 0.f);
    if (deg > 0) {
        int h = lane & 3;
        int eloc = lane >> 2;
        float er_h = er[d * 4 + h];
        int hsel = lane >> 4;  // head owning channels {2*lane, 2*lane+1}

        // ---- pass 1: max only, cache (sid, e) for first 4 chunks ----
        int csid[4];
        float ce[4];
        float m = -1e30f;
#pragma unroll
        for (int c = 0; c < 4; c++) {
            csid[c] = 0; ce[c] = -1e30f;
            int i = c * 16 + eloc;
            if (i < deg) {
                int sid = ssrc[start + i];
                float v = el[sid * 4 + h] + er_h;
                float e = v > 0.f ? v : 0.2f * v;
                csid[c] = sid; ce[c] = e;
                m = fmaxf(m, e);
            }
        }
        for (int base = 64; base < deg; base += 16) {
            int i = base + eloc;
            if (i < deg) {
                int sid = ssrc[start + i];
                float v = el[sid * 4 + h] + er_h;
                float e = v > 0.f ? v : 0.2f * v;
                m = fmaxf(m, e);
            }
        }
        for (int o = 4; o < 64; o <<= 1) m = fmaxf(m, __shfl_xor(m, o));

        // ---- pass 2: exp once, accumulate s and weighted features ----
        float s = 0.f;
#pragma unroll
        for (int c = 0; c < 4; c++) {
            if (c * 16 < deg) {
                int i = c * 16 + eloc;
                float a = (i < deg) ? __expf(ce[c] - m) : 0.f;
                s += a;
                int sid = csid[c];
                int sids[16];
                float a16[16];
#pragma unroll
                for (int j = 0; j < 16; j++) {
                    sids[j] = __builtin_amdgcn_readlane(sid, 4 * j);
                    a16[j] = __shfl(a, 4 * j + hsel, 64);
                }
                unsigned int u[16];
#pragma unroll
                for (int j = 0; j < 16; j++) {
                    u[j] = *(const unsigned int*)(Fb + (size_t)sids[j] * FD + lane * 2);
                }
#pragma unroll
                for (int j = 0; j < 16; j++) {
                    float fx = __uint_as_float(u[j] << 16);
                    float fy = __uint_as_float(u[j] & 0xffff0000u);
                    acc.x = fmaf(a16[j], fx, acc.x);
                    acc.y = fmaf(a16[j], fy, acc.y);
                }
            }
        }
        for (int base = 64; base < deg; base += 16) {
            int i = base + eloc;
            float a = 0.f;
            int sid = 0;
            if (i < deg) {
                sid = ssrc[start + i];
                float v = el[sid * 4 + h] + er_h;
                float e = v > 0.f ? v : 0.2f * v;
                a = __expf(e - m);
            }
            s += a;
            int sids[16];
            float a16[16];
#pragma unroll
            for (int j = 0; j < 16; j++) {
                sids[j] = __builtin_amdgcn_readlane(sid, 4 * j);
                a16[j] = __shfl(a, 4 * j + hsel, 64);
            }
            unsigned int u[16];
#pragma unroll
            for (int j = 0; j < 16; j++) {
                u[j] = *(const unsigned int*)(Fb + (size_t)sids[j] * FD + lane * 2);
            }
#pragma unroll
            for (int j = 0; j < 16; j++) {
                float fx = __uint_as_float(u[j] << 16);
                float fy = __uint_as_float(u[j] & 0xffff0000u);
                acc.x = fmaf(a16[j], fx, acc.x);
                acc.y = fmaf(a16[j], fy, acc.y);
            }
        }
        for (int o = 4; o < 64; o <<= 1) s += __shfl_xor(s, o);
        float inv = 1.f / __shfl(s, hsel, 64);
        acc.x *= inv;
        acc.y *= inv;
    }
    acc.x = fmaxf(acc.x, 0.f);  // relu
    acc.y = fmaxf(acc.y, 0.f);
    if (BF16OUT) {
        unsigned int pk = ((unsigned int)f2bf(acc.y) << 16) | f2bf(acc.x);
        *((unsigned int*)outv + (size_t)d * 64 + lane) = pk;
    } else {
        *((float2*)outv + (size_t)d * 64 + lane) = acc;
    }
}

// ---------------- graph max-pool over nodes (f32 H) ----------------

__global__ void k_pool(const float* __restrict__ H, float* __restrict__ pooled) {
    int t = threadIdx.x;
    int c = t & 127;
    int seg = blockIdx.x * 2 + (t >> 7);
    const int NSEG = 256;
    int rpn = (NN + NSEG - 1) / NSEG;
    int r0 = seg * rpn;
    int r1 = min(NN, r0 + rpn);
    float m = 0.f;
    for (int r = r0; r < r1; ++r) m = fmaxf(m, H[(size_t)r * FD + c]);
    atomicMax((int*)&pooled[c], __float_as_int(m));
}

// ---------------- final FC + softmax ----------------

__global__ void k_final(const float* __restrict__ pooled, const float* __restrict__ Wfc,
                        const float* __restrict__ bfc, float* __restrict__ outp) {
    int lane = threadIdx.x;
    int j = lane & 7;
    int kk = lane >> 3;
    float partial = 0.f;
    for (int k = kk * 16; k < kk * 16 + 16; ++k) partial += pooled[k] * Wfc[k * 8 + j];
    for (int o = 8; o < 64; o <<= 1) partial += __shfl_xor(partial, o);
    float logit = partial + bfc[j];
    float mx = logit;
    for (int o = 1; o < 8; o <<= 1) mx = fmaxf(mx, __shfl_xor(mx, o));
    float ex = __expf(logit - mx);
    float sm = ex;
    for (int o = 1; o < 8; o <<= 1) sm += __shfl_xor(sm, o);
    if (lane < 8) outp[lane] = ex / sm;
}

// ---------------- launch ----------------

extern "C" void kernel_launch(void* const* d_in, const int* in_sizes, int n_in,
                              void* d_out, int out_size, void* d_ws, size_t ws_size,
                              hipStream_t stream) {
    const float* x   = (const float*)d_in[0];
    const int*   src = (const int*)d_in[1];
    const int*   dst = (const int*)d_in[2];
    const float* W1  = (const float*)d_in[3];
    const float* al1 = (const float*)d_in[4];
    const float* ar1 = (const float*)d_in[5];
    const float* W2  = (const float*)d_in[6];
    const float* al2 = (const float*)d_in[7];
    const float* ar2 = (const float*)d_in[8];
    const float* W3  = (const float*)d_in[9];
    const float* al3 = (const float*)d_in[10];
    const float* ar3 = (const float*)d_in[11];
    const float* Wfc = (const float*)d_in[12];
    const float* bfc = (const float*)d_in[13];
    float* out = (float*)d_out;

    char* p = (char*)d_ws;
    auto alloc = [&](size_t bytes) {
        char* r = p;
        p += (bytes + 255) & ~(size_t)255;
        return r;
    };
    unsigned short* Fb = (unsigned short*)alloc((size_t)NN * FD * 2);
    unsigned short* Hb = (unsigned short*)alloc((size_t)NN * FD * 2);  // bf16 H (layers 1,2)
    float* H      = (float*)alloc((size_t)NN * FD * 4);                // f32 H (layer 3)
    float* el     = (float*)alloc((size_t)NN * 4 * 4);
    float* er     = (float*)alloc((size_t)NN * 4 * 4);
    int*   off    = (int*)alloc((size_t)(NN + 1) * 4);
    int*   cnt    = (int*)alloc((size_t)NN * 4);
    int*   bsum   = (int*)alloc(128 * 4);
    int*   ssrc   = (int*)alloc((size_t)NE * 4);
    unsigned int* pairs = (unsigned int*)alloc((size_t)NE * 4);
    int*   gcur   = (int*)alloc((size_t)NB * 4);
    float* pooled = (float*)alloc(128 * 4);
    unsigned short* Wth1 = (unsigned short*)alloc(16384 * 2);
    unsigned short* Wtl1 = (unsigned short*)alloc(16384 * 2);
    unsigned short* Wth2 = (unsigned short*)alloc(16384 * 2);
    unsigned short* Wtl2 = (unsigned short*)alloc(16384 * 2);
    unsigned short* Wth3 = (unsigned short*)alloc(16384 * 2);
    unsigned short* Wtl3 = (unsigned short*)alloc(16384 * 2);

    const int EB = (NE + 255) / 256;
    const int SB = (NN + 1023) / 1024;
    const int GB = (NN + 127) / 128;
    const int AB = (NN + 3) / 4;
    const int BB = (NE + CHUNK - 1) / CHUNK;

    hipMemsetAsync(cnt, 0, (size_t)NN * 4, stream);
    hipMemsetAsync(gcur, 0, (size_t)NB * 4, stream);
    hipMemsetAsync(pooled, 0, 128 * 4, stream);

    k_wsplit<<<64, 256, 0, stream>>>(W1, Wth1, Wtl1);
    k_wsplit<<<64, 256, 0, stream>>>(W2, Wth2, Wtl2);
    k_wsplit<<<64, 256, 0, stream>>>(W3, Wth3, Wtl3);

    k_hist<<<EB, 256, 0, stream>>>(dst, cnt);
    k_scan1<<<SB, 256, 0, stream>>>(cnt, off, bsum);
    k_scan2<<<1, 64, 0, stream>>>(bsum, SB);
    k_add<<<(NN + 256) / 256, 256, 0, stream>>>(off, bsum);
    k_bucket<<<BB, 256, 0, stream>>>(src, dst, off, gcur, pairs);
    k_bsort<<<NB, 256, 0, stream>>>(pairs, off, ssrc);

    // layer 1
    k_gemm_f32<<<GB, 256, 0, stream>>>(x, Wth1, Wtl1, Fb, NN);
    k_scores<<<(NN * 4 + 255) / 256, 256, 0, stream>>>(Fb, al1, ar1, el, er);
    k_agg<1><<<AB, 256, 0, stream>>>(Fb, el, er, off, ssrc, Hb);
    // layer 2
    k_gemm_bf<<<GB, 256, 0, stream>>>(Hb, Wth2, Wtl2, Fb, NN);
    k_scores<<<(NN * 4 + 255) / 256, 256, 0, stream>>>(Fb, al2, ar2, el, er);
    k_agg<1><<<AB, 256, 0, stream>>>(Fb, el, er, off, ssrc, Hb);
    // layer 3 (f32 H -> pool)
    k_gemm_bf<<<GB, 256, 0, stream>>>(Hb, Wth3, Wtl3, Fb, NN);
    k_scores<<<(NN * 4 + 255) / 256, 256, 0, stream>>>(Fb, al3, ar3, el, er);
    k_agg<0><<<AB, 256, 0, stream>>>(Fb, el, er, off, ssrc, H);

    k_pool<<<128, 256, 0, stream>>>(H, pooled);
    k_final<<<1, 64, 0, stream>>>(pooled, Wfc, bfc, out);
}

// Round 7
// 611.658 us; speedup vs baseline: 1.9715x; 1.1207x over previous
//
#include <hip/hip_runtime.h>

#define NN 100000   // nodes
#define NE 1600000  // edges
#define FD 128      // feature dim (4 heads x 32 ch)
#define NB 391      // ceil(NN/256) dst-buckets
#define CHUNK 8192  // edges per bucket-phase block

typedef __attribute__((ext_vector_type(8))) short bf16x8;
typedef __attribute__((ext_vector_type(4))) float f32x4;

union B8 { bf16x8 v; unsigned int u[4]; };

// ---------------- helpers ----------------

__device__ __forceinline__ unsigned short f2bf(float x) {
    unsigned int u = __float_as_uint(x);
    u += 0x7fffu + ((u >> 16) & 1u);   // round-to-nearest-even
    return (unsigned short)(u >> 16);
}

__device__ __forceinline__ unsigned int pkhi(unsigned int ua, unsigned int ub) {
    return __builtin_amdgcn_perm(ub, ua, 0x07060302);
}

// truncation hi/lo split of 8 f32 -> bf16x8 hi, lo.  x ~= hi + lo to ~2^-14 rel.
__device__ __forceinline__ void split8(const float4& x0, const float4& x1,
                                       bf16x8& hi, bf16x8& lo) {
    float f[8] = {x0.x, x0.y, x0.z, x0.w, x1.x, x1.y, x1.z, x1.w};
    B8 H, L;
#pragma unroll
    for (int i = 0; i < 4; i++) {
        unsigned int ua = __float_as_uint(f[2 * i]);
        unsigned int ub = __float_as_uint(f[2 * i + 1]);
        H.u[i] = pkhi(ua, ub);
        float ra = f[2 * i]     - __uint_as_float(ua & 0xffff0000u);
        float rb = f[2 * i + 1] - __uint_as_float(ub & 0xffff0000u);
        L.u[i] = pkhi(__float_as_uint(ra), __float_as_uint(rb));
    }
    hi = H.v; lo = L.v;
}

// ---------------- sort chain: bucket counts -> scan -> scatter -> per-bucket sort ----------------

__global__ __launch_bounds__(256) void k_bcnt(const int* __restrict__ dst, int* __restrict__ bcnt) {
    __shared__ int scnt[NB];
    int t = threadIdx.x;
    for (int i = t; i < NB; i += 256) scnt[i] = 0;
    __syncthreads();
    int e0 = blockIdx.x * CHUNK;
    int e1 = min(e0 + CHUNK, NE);
    for (int i = e0 + t; i < e1; i += 256) atomicAdd(&scnt[dst[i] >> 8], 1);
    __syncthreads();
    for (int i = t; i < NB; i += 256)
        if (scnt[i]) atomicAdd(&bcnt[i], scnt[i]);
}

__global__ __launch_bounds__(512) void k_bscan(const int* __restrict__ bcnt,
                                               int* __restrict__ bbase, int* __restrict__ off) {
    __shared__ int sh[512];
    int t = threadIdx.x;
    int v = (t < NB) ? bcnt[t] : 0;
    sh[t] = v;
    __syncthreads();
    for (int o = 1; o < 512; o <<= 1) {
        int x = (t >= o) ? sh[t - o] : 0;
        __syncthreads();
        sh[t] += x;
        __syncthreads();
    }
    if (t < NB) bbase[t] = sh[t] - v;   // exclusive prefix
    if (t == NB) bbase[NB] = NE;
    if (t == 0) off[NN] = NE;
}

// pairs[pos] = src | (dst&255)<<17
__global__ __launch_bounds__(256) void k_bucket(const int* __restrict__ src,
                                                const int* __restrict__ dst,
                                                const int* __restrict__ bbase,
                                                int* __restrict__ gcur,
                                                unsigned int* __restrict__ pairs) {
    __shared__ int scnt[NB];
    __shared__ int sbase[NB];
    int t = threadIdx.x;
    for (int i = t; i < NB; i += 256) scnt[i] = 0;
    __syncthreads();
    int e0 = blockIdx.x * CHUNK;
    int e1 = min(e0 + CHUNK, NE);
    for (int i = e0 + t; i < e1; i += 256) atomicAdd(&scnt[dst[i] >> 8], 1);
    __syncthreads();
    for (int i = t; i < NB; i += 256) {
        int c = scnt[i];
        sbase[i] = (c > 0) ? (bbase[i] + atomicAdd(&gcur[i], c)) : 0;
        scnt[i] = 0;  // reuse as local cursor
    }
    __syncthreads();
    for (int i = e0 + t; i < e1; i += 256) {
        int d = dst[i];
        int b = d >> 8;
        int r = atomicAdd(&scnt[b], 1);
        pairs[sbase[b] + r] = (unsigned int)src[i] | ((unsigned int)(d & 255) << 17);
    }
}

// per-bucket: node histogram + scan (writes CSR off) + scatter ssrc
__global__ __launch_bounds__(256) void k_bsort(const unsigned int* __restrict__ pairs,
                                               const int* __restrict__ bbase,
                                               int* __restrict__ off,
                                               int* __restrict__ ssrc) {
    __shared__ int hcnt[256];
    __shared__ int cur[256];
    int t = threadIdx.x;
    int b = blockIdx.x;
    hcnt[t] = 0;
    __syncthreads();
    int estart = bbase[b], eend = bbase[b + 1];
    for (int i = estart + t; i < eend; i += 256)
        atomicAdd(&hcnt[(pairs[i] >> 17) & 255], 1);
    __syncthreads();
    int v = hcnt[t];
    cur[t] = v;
    __syncthreads();
    for (int o = 1; o < 256; o <<= 1) {
        int x = (t >= o) ? cur[t - o] : 0;
        __syncthreads();
        cur[t] += x;
        __syncthreads();
    }
    int excl = cur[t] - v;
    int node = (b << 8) + t;
    if (node < NN) off[node] = estart + excl;
    __syncthreads();
    cur[t] = estart + excl;
    __syncthreads();
    for (int i = estart + t; i < eend; i += 256) {
        unsigned int p = pairs[i];
        int ldst = (p >> 17) & 255;
        int pos = atomicAdd(&cur[ldst], 1);
        ssrc[pos] = (int)(p & 0x1ffffu);
    }
}

// ---------------- W pre-split (all 3 layers, one dispatch) ----------------

__global__ void k_wsplit3(const float* __restrict__ W1, const float* __restrict__ W2,
                          const float* __restrict__ W3, unsigned short* __restrict__ Wth,
                          unsigned short* __restrict__ Wtl) {
    int gid = blockIdx.x * 256 + threadIdx.x;  // 0..49151
    int w = gid >> 14;
    int tid = gid & 16383;
    const float* W = (w == 0) ? W1 : (w == 1) ? W2 : W3;
    int n = tid >> 7, k = tid & 127;
    float val = W[k * 128 + n];
    unsigned short h = f2bf(val);
    float res = val - __uint_as_float((unsigned int)h << 16);
    Wth[gid] = h;
    Wtl[gid] = f2bf(res);
}

// ---------------- fused GEMM epilogue: bf16 features + el/er scores ----------------
// C layout: row = row0 + g*16 + q*4 + i, col = nt*16 + r.
// el[row][h] = sum over that head's 32 cols of acc * al[h][col&31]; xor-reduce over r.

__device__ __forceinline__ void epilogue(f32x4 acc[2][8], int row0, int q, int r, int nrows,
                                         const float* __restrict__ al,
                                         const float* __restrict__ ar,
                                         unsigned short* __restrict__ Fb,
                                         float* __restrict__ el, float* __restrict__ er) {
#pragma unroll
    for (int g = 0; g < 2; g++) {
#pragma unroll
        for (int i = 0; i < 4; i++) {
            int row = row0 + g * 16 + q * 4 + i;
            float elp[4], erp[4];
#pragma unroll
            for (int h = 0; h < 4; h++) { elp[h] = 0.f; erp[h] = 0.f; }
#pragma unroll
            for (int nt = 0; nt < 8; nt++) {
                int h = nt >> 1;
                int c = ((nt & 1) << 4) + r;
                float v = acc[g][nt][i];
                elp[h] = fmaf(v, al[h * 32 + c], elp[h]);
                erp[h] = fmaf(v, ar[h * 32 + c], erp[h]);
            }
#pragma unroll
            for (int o = 1; o < 16; o <<= 1) {
#pragma unroll
                for (int h = 0; h < 4; h++) {
                    elp[h] += __shfl_xor(elp[h], o);
                    erp[h] += __shfl_xor(erp[h], o);
                }
            }
            if (row < nrows) {
#pragma unroll
                for (int nt = 0; nt < 8; nt++)
                    Fb[(size_t)row * FD + nt * 16 + r] = f2bf(acc[g][nt][i]);
                int hh = r & 3;
                float ve = (hh & 2) ? ((hh & 1) ? elp[3] : elp[2]) : ((hh & 1) ? elp[1] : elp[0]);
                float vr = (hh & 2) ? ((hh & 1) ? erp[3] : erp[2]) : ((hh & 1) ? erp[1] : erp[0]);
                if (r < 4) el[row * 4 + hh] = ve;
                else if (r < 8) er[row * 4 + hh] = vr;
            }
        }
    }
}

// ---------------- MFMA GEMM (layer 1): A f32, hi/lo split both sides ----------------

__global__ __launch_bounds__(256) void k_gemm_f32(const float* __restrict__ A,
                                                  const unsigned short* __restrict__ Wth,
                                                  const unsigned short* __restrict__ Wtl,
                                                  unsigned short* __restrict__ Fb, int nrows,
                                                  const float* __restrict__ al,
                                                  const float* __restrict__ ar,
                                                  float* __restrict__ el,
                                                  float* __restrict__ er) {
    int t = threadIdx.x;
    int wave = t >> 6, lane = t & 63;
    int r = lane & 15, q = lane >> 4;
    int row0 = blockIdx.x * 128 + wave * 32;
    int rg0 = row0 + r, rg1 = row0 + 16 + r;

    f32x4 acc[2][8];
#pragma unroll
    for (int g = 0; g < 2; g++)
#pragma unroll
        for (int nt = 0; nt < 8; nt++) acc[g][nt] = (f32x4){0.f, 0.f, 0.f, 0.f};

#pragma unroll
    for (int ks = 0; ks < 4; ks++) {
        int k0 = ks * 32 + q * 8;
        float4 z = make_float4(0.f, 0.f, 0.f, 0.f);
        float4 a0 = z, a1 = z, b0 = z, b1 = z;
        if (rg0 < nrows) {
            const float* pa = A + (size_t)rg0 * FD + k0;
            a0 = *(const float4*)pa;
            a1 = *(const float4*)(pa + 4);
        }
        if (rg1 < nrows) {
            const float* pb = A + (size_t)rg1 * FD + k0;
            b0 = *(const float4*)pb;
            b1 = *(const float4*)(pb + 4);
        }
        bf16x8 ah0, al0, ah1, al1;
        split8(a0, a1, ah0, al0);
        split8(b0, b1, ah1, al1);
#pragma unroll
        for (int nt = 0; nt < 8; nt++) {
            int wo = ((nt * 16 + r) << 7) + k0;
            bf16x8 bh = *(const bf16x8*)(Wth + wo);
            bf16x8 bl = *(const bf16x8*)(Wtl + wo);
            acc[0][nt] = __builtin_amdgcn_mfma_f32_16x16x32_bf16(ah0, bh, acc[0][nt], 0, 0, 0);
            acc[0][nt] = __builtin_amdgcn_mfma_f32_16x16x32_bf16(al0, bh, acc[0][nt], 0, 0, 0);
            acc[0][nt] = __builtin_amdgcn_mfma_f32_16x16x32_bf16(ah0, bl, acc[0][nt], 0, 0, 0);
            acc[1][nt] = __builtin_amdgcn_mfma_f32_16x16x32_bf16(ah1, bh, acc[1][nt], 0, 0, 0);
            acc[1][nt] = __builtin_amdgcn_mfma_f32_16x16x32_bf16(al1, bh, acc[1][nt], 0, 0, 0);
            acc[1][nt] = __builtin_amdgcn_mfma_f32_16x16x32_bf16(ah1, bl, acc[1][nt], 0, 0, 0);
        }
    }
    epilogue(acc, row0, q, r, nrows, al, ar, Fb, el, er);
}

// ---------------- MFMA GEMM (layers 2,3): A bf16, W hi/lo -> 2 MFMAs ----------------

__global__ __launch_bounds__(256) void k_gemm_bf(const unsigned short* __restrict__ A,
                                                 const unsigned short* __restrict__ Wth,
                                                 const unsigned short* __restrict__ Wtl,
                                                 unsigned short* __restrict__ Fb, int nrows,
                                                 const float* __restrict__ al,
                                                 const float* __restrict__ ar,
                                                 float* __restrict__ el,
                                                 float* __restrict__ er) {
    int t = threadIdx.x;
    int wave = t >> 6, lane = t & 63;
    int r = lane & 15, q = lane >> 4;
    int row0 = blockIdx.x * 128 + wave * 32;
    int rg0 = row0 + r, rg1 = row0 + 16 + r;

    f32x4 acc[2][8];
#pragma unroll
    for (int g = 0; g < 2; g++)
#pragma unroll
        for (int nt = 0; nt < 8; nt++) acc[g][nt] = (f32x4){0.f, 0.f, 0.f, 0.f};

#pragma unroll
    for (int ks = 0; ks < 4; ks++) {
        int k0 = ks * 32 + q * 8;
        bf16x8 a0 = {0, 0, 0, 0, 0, 0, 0, 0};
        bf16x8 a1 = {0, 0, 0, 0, 0, 0, 0, 0};
        if (rg0 < nrows) a0 = *(const bf16x8*)(A + (size_t)rg0 * FD + k0);
        if (rg1 < nrows) a1 = *(const bf16x8*)(A + (size_t)rg1 * FD + k0);
#pragma unroll
        for (int nt = 0; nt < 8; nt++) {
            int wo = ((nt * 16 + r) << 7) + k0;
            bf16x8 bh = *(const bf16x8*)(Wth + wo);
            bf16x8 bl = *(const bf16x8*)(Wtl + wo);
            acc[0][nt] = __builtin_amdgcn_mfma_f32_16x16x32_bf16(a0, bh, acc[0][nt], 0, 0, 0);
            acc[0][nt] = __builtin_amdgcn_mfma_f32_16x16x32_bf16(a0, bl, acc[0][nt], 0, 0, 0);
            acc[1][nt] = __builtin_amdgcn_mfma_f32_16x16x32_bf16(a1, bh, acc[1][nt], 0, 0, 0);
            acc[1][nt] = __builtin_amdgcn_mfma_f32_16x16x32_bf16(a1, bl, acc[1][nt], 0, 0, 0);
        }
    }
    epilogue(acc, row0, q, r, nrows, al, ar, Fb, el, er);
}

// ---------------- aggregation: one wave per dst node ----------------

template <int BF16OUT>
__global__ __launch_bounds__(256) void k_agg(const unsigned short* __restrict__ Fb,
                                             const float* __restrict__ el,
                                             const float* __restrict__ er,
                                             const int* __restrict__ off,
                                             const int* __restrict__ ssrc,
                                             void* __restrict__ outv) {
    int wave = threadIdx.x >> 6;
    int lane = threadIdx.x & 63;
    int d = blockIdx.x * 4 + wave;
    if (d >= NN) return;
    int start = off[d];
    int deg = off[d + 1] - start;
    float2 acc = make_float2(0.f, 0.f);
    if (deg > 0) {
        int h = lane & 3;
        int eloc = lane >> 2;
        float er_h = er[d * 4 + h];
        int hsel = lane >> 4;

        int csid[4];
        float ce[4];
        float m = -1e30f;
#pragma unroll
        for (int c = 0; c < 4; c++) {
            csid[c] = 0; ce[c] = -1e30f;
            int i = c * 16 + eloc;
            if (i < deg) {
                int sid = ssrc[start + i];
                float v = el[sid * 4 + h] + er_h;
                float e = v > 0.f ? v : 0.2f * v;
                csid[c] = sid; ce[c] = e;
                m = fmaxf(m, e);
            }
        }
        for (int base = 64; base < deg; base += 16) {
            int i = base + eloc;
            if (i < deg) {
                int sid = ssrc[start + i];
                float v = el[sid * 4 + h] + er_h;
                float e = v > 0.f ? v : 0.2f * v;
                m = fmaxf(m, e);
            }
        }
        for (int o = 4; o < 64; o <<= 1) m = fmaxf(m, __shfl_xor(m, o));

        float s = 0.f;
#pragma unroll
        for (int c = 0; c < 4; c++) {
            if (c * 16 < deg) {
                int i = c * 16 + eloc;
                float a = (i < deg) ? __expf(ce[c] - m) : 0.f;
                s += a;
                int sid = csid[c];
                int sids[16];
                float a16[16];
#pragma unroll
                for (int j = 0; j < 16; j++) {
                    sids[j] = __builtin_amdgcn_readlane(sid, 4 * j);
                    a16[j] = __shfl(a, 4 * j + hsel, 64);
                }
                unsigned int u[16];
#pragma unroll
                for (int j = 0; j < 16; j++) {
                    u[j] = *(const unsigned int*)(Fb + (size_t)sids[j] * FD + lane * 2);
                }
#pragma unroll
                for (int j = 0; j < 16; j++) {
                    float fx = __uint_as_float(u[j] << 16);
                    float fy = __uint_as_float(u[j] & 0xffff0000u);
                    acc.x = fmaf(a16[j], fx, acc.x);
                    acc.y = fmaf(a16[j], fy, acc.y);
                }
            }
        }
        for (int base = 64; base < deg; base += 16) {
            int i = base + eloc;
            float a = 0.f;
            int sid = 0;
            if (i < deg) {
                sid = ssrc[start + i];
                float v = el[sid * 4 + h] + er_h;
                float e = v > 0.f ? v : 0.2f * v;
                a = __expf(e - m);
            }
            s += a;
            int sids[16];
            float a16[16];
#pragma unroll
            for (int j = 0; j < 16; j++) {
                sids[j] = __builtin_amdgcn_readlane(sid, 4 * j);
                a16[j] = __shfl(a, 4 * j + hsel, 64);
            }
            unsigned int u[16];
#pragma unroll
            for (int j = 0; j < 16; j++) {
                u[j] = *(const unsigned int*)(Fb + (size_t)sids[j] * FD + lane * 2);
            }
#pragma unroll
            for (int j = 0; j < 16; j++) {
                float fx = __uint_as_float(u[j] << 16);
                float fy = __uint_as_float(u[j] & 0xffff0000u);
                acc.x = fmaf(a16[j], fx, acc.x);
                acc.y = fmaf(a16[j], fy, acc.y);
            }
        }
        for (int o = 4; o < 64; o <<= 1) s += __shfl_xor(s, o);
        float inv = 1.f / __shfl(s, hsel, 64);
        acc.x *= inv;
        acc.y *= inv;
    }
    acc.x = fmaxf(acc.x, 0.f);
    acc.y = fmaxf(acc.y, 0.f);
    if (BF16OUT) {
        unsigned int pk = ((unsigned int)f2bf(acc.y) << 16) | f2bf(acc.x);
        *((unsigned int*)outv + (size_t)d * 64 + lane) = pk;
    } else {
        *((float2*)outv + (size_t)d * 64 + lane) = acc;
    }
}

// ---------------- graph max-pool over nodes (f32 H) ----------------

__global__ void k_pool(const float* __restrict__ H, float* __restrict__ pooled) {
    int t = threadIdx.x;
    int c = t & 127;
    int seg = blockIdx.x * 2 + (t >> 7);
    const int NSEG = 256;
    int rpn = (NN + NSEG - 1) / NSEG;
    int r0 = seg * rpn;
    int r1 = min(NN, r0 + rpn);
    float m = 0.f;
    for (int r = r0; r < r1; ++r) m = fmaxf(m, H[(size_t)r * FD + c]);
    atomicMax((int*)&pooled[c], __float_as_int(m));
}

// ---------------- final FC + softmax ----------------

__global__ void k_final(const float* __restrict__ pooled, const float* __restrict__ Wfc,
                        const float* __restrict__ bfc, float* __restrict__ outp) {
    int lane = threadIdx.x;
    int j = lane & 7;
    int kk = lane >> 3;
    float partial = 0.f;
    for (int k = kk * 16; k < kk * 16 + 16; ++k) partial += pooled[k] * Wfc[k * 8 + j];
    for (int o = 8; o < 64; o <<= 1) partial += __shfl_xor(partial, o);
    float logit = partial + bfc[j];
    float mx = logit;
    for (int o = 1; o < 8; o <<= 1) mx = fmaxf(mx, __shfl_xor(mx, o));
    float ex = __expf(logit - mx);
    float sm = ex;
    for (int o = 1; o < 8; o <<= 1) sm += __shfl_xor(sm, o);
    if (lane < 8) outp[lane] = ex / sm;
}

// ---------------- launch ----------------

extern "C" void kernel_launch(void* const* d_in, const int* in_sizes, int n_in,
                              void* d_out, int out_size, void* d_ws, size_t ws_size,
                              hipStream_t stream) {
    const float* x   = (const float*)d_in[0];
    const int*   src = (const int*)d_in[1];
    const int*   dst = (const int*)d_in[2];
    const float* W1  = (const float*)d_in[3];
    const float* al1 = (const float*)d_in[4];
    const float* ar1 = (const float*)d_in[5];
    const float* W2  = (const float*)d_in[6];
    const float* al2 = (const float*)d_in[7];
    const float* ar2 = (const float*)d_in[8];
    const float* W3  = (const float*)d_in[9];
    const float* al3 = (const float*)d_in[10];
    const float* ar3 = (const float*)d_in[11];
    const float* Wfc = (const float*)d_in[12];
    const float* bfc = (const float*)d_in[13];
    float* out = (float*)d_out;

    char* p = (char*)d_ws;
    auto alloc = [&](size_t bytes) {
        char* r = p;
        p += (bytes + 255) & ~(size_t)255;
        return r;
    };
    unsigned short* Fb = (unsigned short*)alloc((size_t)NN * FD * 2);
    unsigned short* Hb = (unsigned short*)alloc((size_t)NN * FD * 2);
    float* H      = (float*)alloc((size_t)NN * FD * 4);
    float* el     = (float*)alloc((size_t)NN * 4 * 4);
    float* er     = (float*)alloc((size_t)NN * 4 * 4);
    int*   off    = (int*)alloc((size_t)(NN + 1) * 4);
    int*   ssrc   = (int*)alloc((size_t)NE * 4);
    unsigned int* pairs = (unsigned int*)alloc((size_t)NE * 4);
    int*   bcnt   = (int*)alloc((size_t)NB * 4);
    int*   bbase  = (int*)alloc((size_t)(NB + 1) * 4);
    int*   gcur   = (int*)alloc((size_t)NB * 4);
    float* pooled = (float*)alloc(128 * 4);
    unsigned short* Wth = (unsigned short*)alloc(3 * 16384 * 2);
    unsigned short* Wtl = (unsigned short*)alloc(3 * 16384 * 2);

    const int GB = (NN + 127) / 128;
    const int AB = (NN + 3) / 4;
    const int BB = (NE + CHUNK - 1) / CHUNK;  // 196

    hipMemsetAsync(bcnt, 0, (size_t)NB * 4, stream);
    hipMemsetAsync(gcur, 0, (size_t)NB * 4, stream);
    hipMemsetAsync(pooled, 0, 128 * 4, stream);

    k_wsplit3<<<192, 256, 0, stream>>>(W1, W2, W3, Wth, Wtl);
    k_bcnt<<<BB, 256, 0, stream>>>(dst, bcnt);
    k_bscan<<<1, 512, 0, stream>>>(bcnt, bbase, off);
    k_bucket<<<BB, 256, 0, stream>>>(src, dst, bbase, gcur, pairs);
    k_bsort<<<NB, 256, 0, stream>>>(pairs, bbase, off, ssrc);

    // layer 1
    k_gemm_f32<<<GB, 256, 0, stream>>>(x, Wth, Wtl, Fb, NN, al1, ar1, el, er);
    k_agg<1><<<AB, 256, 0, stream>>>(Fb, el, er, off, ssrc, Hb);
    // layer 2
    k_gemm_bf<<<GB, 256, 0, stream>>>(Hb, Wth + 16384, Wtl + 16384, Fb, NN, al2, ar2, el, er);
    k_agg<1><<<AB, 256, 0, stream>>>(Fb, el, er, off, ssrc, Hb);
    // layer 3 (f32 H -> pool)
    k_gemm_bf<<<GB, 256, 0, stream>>>(Hb, Wth + 32768, Wtl + 32768, Fb, NN, al3, ar3, el, er);
    k_agg<0><<<AB, 256, 0, stream>>>(Fb, el, er, off, ssrc, H);

    k_pool<<<128, 256, 0, stream>>>(H, pooled);
    k_final<<<1, 64, 0, stream>>>(pooled, Wfc, bfc, out);
}